// Round 1
// baseline (76496.490 us; speedup 1.0000x reference)
//
#include <hip/hip_runtime.h>
#include <float.h>

constexpr int SEQ  = 128;   // sentence length T
constexpr int D    = 256;   // DIM / STATEDIM
constexpr int G    = 1024;  // 4*DIM gate width
constexpr int NREL = 26;    // REL_COUNT + 1
constexpr int NENT = 7;

// ---------------------------------------------------------------------------
// Generic strided transpose: out[k*rows + i] = in[i*in_stride + in_off + k]
// ---------------------------------------------------------------------------
__global__ void k_trans(const float* __restrict__ in, float* __restrict__ out,
                        int rows, int cols, int in_stride, int in_off)
{
    int idx = blockIdx.x * 256 + threadIdx.x;
    if (idx >= rows * cols) return;
    int i = idx % rows;
    int k = idx / rows;
    out[idx] = in[(size_t)i * in_stride + in_off + k];
}

// ---------------------------------------------------------------------------
// xg[t][j] = bih[j] + bhh[j] + sum_k wordvector[text[t]][k] * Wih[j][k]
// grid = SEQ blocks, 1024 threads
// ---------------------------------------------------------------------------
__global__ __launch_bounds__(1024) void k_xg(
    const int* __restrict__ text, const float* __restrict__ wv,
    const float* __restrict__ Wih, const float* __restrict__ bih,
    const float* __restrict__ bhh, float* __restrict__ xg)
{
    int t = blockIdx.x, j = threadIdx.x;
    const float* x  = wv + (size_t)text[t] * D;
    const float* wr = Wih + (size_t)j * D;
    float acc = bih[j] + bhh[j];
    for (int k = 0; k < D; ++k) acc += x[k] * wr[k];
    xg[t * G + j] = acc;
}

// ---------------------------------------------------------------------------
// Sequential LSTM, one block per direction (grid=2), 1024 threads.
// WHT is Whh transposed: WHT[k*G + j] = Whh[j][k]  (coalesced over j).
// wordin[t][dir*D + i] = h_t[i]
// ---------------------------------------------------------------------------
__global__ __launch_bounds__(1024) void k_lstm(
    const float* __restrict__ xgF, const float* __restrict__ xgB,
    const float* __restrict__ WHTF, const float* __restrict__ WHTB,
    float* __restrict__ wordin)
{
    int dir = blockIdx.x;
    const float* xg  = dir ? xgB  : xgF;
    const float* WHT = dir ? WHTB : WHTF;
    __shared__ float h[D], c[D], g[G];
    int j = threadIdx.x;
    if (j < D) { h[j] = 0.f; c[j] = 0.f; }
    __syncthreads();
    for (int s = 0; s < SEQ; ++s) {
        int t = dir ? (SEQ - 1 - s) : s;
        float acc = xg[t * G + j];
        for (int k = 0; k < D; ++k) acc += WHT[k * G + j] * h[k];
        g[j] = acc;
        __syncthreads();
        if (j < D) {
            float si = 1.f / (1.f + expf(-g[j]));
            float sf = 1.f / (1.f + expf(-g[D + j]));
            float gg = tanhf(g[2 * D + j]);
            float so = 1.f / (1.f + expf(-g[3 * D + j]));
            float cn = sf * c[j] + si * gg;
            float hn = so * tanhf(cn);
            c[j] = cn; h[j] = hn;
            wordin[t * (2 * D) + dir * D + j] = hn;
        }
        __syncthreads();
    }
}

// ---------------------------------------------------------------------------
// Parallel precompute after LSTM:
//  blocks 0..127   : TW[t][i] = bt[i] + sum_{j<512} wordin[t][j]*Wt[i][j]
//                    BW[t][i] = bb[i] + sum_{j<512} wordin[t][j]*Wb[i][j]
//  blocks 128..153 : RV[r][i] = sum_k relvec[r][k]*Wt[i][512+k]
//  blocks 154..160 : EV[e][i] = sum_k entvec[e][k]*Wb[i][512+k]
// Uses pre-transposed WTWT/WBWT/WTRT/WBET for coalesced reads.
// ---------------------------------------------------------------------------
__global__ __launch_bounds__(256) void k_prep2(
    const float* __restrict__ wordin,
    const float* __restrict__ WTWT, const float* __restrict__ WBWT,
    const float* __restrict__ WTRT, const float* __restrict__ WBET,
    const float* __restrict__ relvec, const float* __restrict__ entvec,
    const float* __restrict__ btv, const float* __restrict__ bbv,
    float* __restrict__ TW, float* __restrict__ BW,
    float* __restrict__ RV, float* __restrict__ EV)
{
    int b = blockIdx.x, i = threadIdx.x;
    if (b < SEQ) {
        const float* w = wordin + b * (2 * D);
        float a1 = btv[i], a2 = bbv[i];
        for (int j = 0; j < 2 * D; ++j) {
            float wv = w[j];
            a1 += wv * WTWT[j * D + i];
            a2 += wv * WBWT[j * D + i];
        }
        TW[b * D + i] = a1;
        BW[b * D + i] = a2;
    } else if (b < SEQ + NREL) {
        int r = b - SEQ;
        const float* x = relvec + r * D;
        float a = 0.f;
        for (int k = 0; k < D; ++k) a += x[k] * WTRT[k * D + i];
        RV[r * D + i] = a;
    } else {
        int e = b - SEQ - NREL;
        const float* x = entvec + e * D;
        float a = 0.f;
        for (int k = 0; k < D; ++k) a += x[k] * WBET[k * D + i];
        EV[e * D + i] = a;
    }
}

// ---------------------------------------------------------------------------
// Wave-level softmax + first-occurrence argmax over n<=64 logits.
// Mimics reference: p = exp(l - max)/sum (IEEE div), argmax over p.
// All 64 lanes of the wave must be active. Lanes >= n pass lv = -FLT_MAX.
// ---------------------------------------------------------------------------
__device__ inline void wave_smax(float lv, int n, int lane, int& am, float& pmax)
{
    float mx = lv;
    #pragma unroll
    for (int off = 32; off; off >>= 1) mx = fmaxf(mx, __shfl_xor(mx, off));
    float e  = (lane < n) ? expf(lv - mx) : 0.f;
    float se = e;
    #pragma unroll
    for (int off = 32; off; off >>= 1) se += __shfl_xor(se, off);
    float p  = (lane < n) ? (e / se) : -1.f;
    float pm = p;
    #pragma unroll
    for (int off = 32; off; off >>= 1) pm = fmaxf(pm, __shfl_xor(pm, off));
    unsigned long long mask = __ballot(p == pm);
    am = __ffsll((unsigned long long)mask) - 1;
    pmax = pm;
}

// ---------------------------------------------------------------------------
// Sequential main kernel: 1 block, 256 threads (1 wave/SIMD, big VGPR budget).
// Wb_m^T held fully in registers (256 VGPR/thread).
// ---------------------------------------------------------------------------
__global__ __launch_bounds__(256, 1) void k_main(
    const float* __restrict__ TW,   const float* __restrict__ BW,
    const float* __restrict__ RV,   const float* __restrict__ EV,
    const float* __restrict__ WTMT, const float* __restrict__ WTTT,
    const float* __restrict__ WTBT, const float* __restrict__ WBTT,
    const float* __restrict__ WBMT, const float* __restrict__ WBGT,
    const float* __restrict__ Wp,   const float* __restrict__ bp,
    const float* __restrict__ Wpl,  const float* __restrict__ bpl,
    const float* __restrict__ btt,  const float* __restrict__ btb,
    const float* __restrict__ bbt,  float* __restrict__ out)
{
    int i = threadIdx.x;
    int lane = i & 63;
    __shared__ float mem[D], outv[D], membL[D], tgt[D];
    __shared__ float logitsL[32];
    __shared__ float Esh[NENT * D], WrSh[NENT * D], brSh[8];
    __shared__ int scal[4];   // 0: action, 1: rel, 2: ab

    // Wb_m^T column i in registers: wbm[k] = Wb[i][768+k]
    float wbm[D];
    #pragma unroll
    for (int k = 0; k < D; ++k) wbm[k] = WBMT[k * D + i];
    for (int k = i; k < NENT * D; k += 256) Esh[k] = EV[k];
    mem[i] = 0.f;
    if (i == 0) { scal[0] = 0; scal[1] = 0; scal[2] = 0; }
    __syncthreads();

    for (int t = 0; t < SEQ; ++t) {
        // ---- top step: outp = tanh(TW[t] + RV[rel] + Wt_m @ mem) ----
        int rel = scal[1];
        float a = TW[t * D + i] + RV[rel * D + i];
        for (int k = 0; k < D; ++k) a += WTMT[k * D + i] * mem[k];
        outv[i] = tanhf(a);
        __syncthreads();

        // ---- 26-way logits ----
        {
            int r = i >> 5, ln = i & 31;
            for (int rr = r; rr < NREL; rr += 8) {
                const float* wr = Wp + rr * D;
                float p = 0.f;
                for (int k = ln; k < D; k += 32) p += outv[k] * wr[k];
                #pragma unroll
                for (int off = 16; off; off >>= 1) p += __shfl_down(p, off, 32);
                if (ln == 0) logitsL[rr] = p + bp[rr];
            }
        }
        __syncthreads();
        if (i < 64) {
            float lv = (lane < NREL) ? logitsL[lane] : -FLT_MAX;
            int am; float pm;
            wave_smax(lv, NREL, lane, am, pm);
            if (i == 0) {
                out[t] = (float)am;
                out[SEQ + t] = pm;
                scal[0] = am;
                if (am > 0) scal[1] = am;
            }
        }
        __syncthreads();
        int action = scal[0];

        if (action > 0) {
            // target = Wtt@outp + btt ; memb0 = Wtb@outp + btb
            float a1 = btt[i], a2 = btb[i];
            for (int k = 0; k < D; ++k) {
                float v = outv[k];
                a1 += WTTT[k * D + i] * v;
                a2 += WTBT[k * D + i] * v;
            }
            tgt[i] = a1;
            membL[i] = a2;
            {
                size_t base = (size_t)(action - 1) * NENT * D;
                for (int k = i; k < NENT * D; k += 256) WrSh[k] = Wpl[base + k];
                if (i < NENT) brSh[i] = bpl[(action - 1) * NENT + i];
            }
            __syncthreads();
            // constant target-term: Wb_tg @ target
            float btm = 0.f;
            for (int k = 0; k < D; ++k) btm += WBGT[k * D + i] * tgt[k];

            int ab = 0;
            for (int s = 0; s < SEQ; ++s) {
                float acc = BW[s * D + i] + Esh[ab * D + i] + btm;
                #pragma unroll
                for (int k = 0; k < D; ++k) acc += wbm[k] * membL[k];
                float ob = tanhf(acc);
                __syncthreads();
                membL[i] = ob;
                __syncthreads();
                {
                    int r = i >> 5, ln = i & 31;
                    if (r < NENT) {
                        const float* wr = WrSh + r * D;
                        float p = 0.f;
                        for (int k = ln; k < D; k += 32) p += membL[k] * wr[k];
                        #pragma unroll
                        for (int off = 16; off; off >>= 1) p += __shfl_down(p, off, 32);
                        if (ln == 0) logitsL[r] = p + brSh[r];
                    }
                }
                __syncthreads();
                if (i < 64) {
                    float lv = (lane < NENT) ? logitsL[lane] : -FLT_MAX;
                    int am; float pm;
                    wave_smax(lv, NENT, lane, am, pm);
                    if (i == 0) {
                        out[2 * SEQ + t * SEQ + s] = (float)am;
                        out[2 * SEQ + SEQ * SEQ + t * SEQ + s] = pm;
                        scal[2] = am;
                    }
                }
                __syncthreads();
                ab = scal[2];
            }
            // mem = Wbt @ membf + bbt
            float a4 = bbt[i];
            for (int k = 0; k < D; ++k) a4 += WBTT[k * D + i] * membL[k];
            mem[i] = a4;
        } else {
            if (i < SEQ) {
                out[2 * SEQ + t * SEQ + i] = 0.f;
                out[2 * SEQ + SEQ * SEQ + t * SEQ + i] = 0.f;
            }
            mem[i] = outv[i];
        }
        __syncthreads();
    }
}

// ---------------------------------------------------------------------------
extern "C" void kernel_launch(void* const* d_in, const int* in_sizes, int n_in,
                              void* d_out, int out_size, void* d_ws, size_t ws_size,
                              hipStream_t stream)
{
    (void)in_sizes; (void)n_in; (void)out_size; (void)ws_size;
    const int*   text       = (const int*)  d_in[0];
    const float* wordvector = (const float*)d_in[1];
    const float* relvec     = (const float*)d_in[2];
    const float* entvec     = (const float*)d_in[3];
    const float* WihL = (const float*)d_in[4];  const float* WhhL = (const float*)d_in[5];
    const float* bihL = (const float*)d_in[6];  const float* bhhL = (const float*)d_in[7];
    const float* WihR = (const float*)d_in[8];  const float* WhhR = (const float*)d_in[9];
    const float* bihR = (const float*)d_in[10]; const float* bhhR = (const float*)d_in[11];
    const float* Wt   = (const float*)d_in[12]; const float* bt   = (const float*)d_in[13];
    const float* Wp   = (const float*)d_in[14]; const float* bp   = (const float*)d_in[15];
    const float* Wb   = (const float*)d_in[16]; const float* bb   = (const float*)d_in[17];
    const float* Wpl  = (const float*)d_in[18]; const float* bpl  = (const float*)d_in[19];
    const float* Wtt  = (const float*)d_in[20]; const float* btt  = (const float*)d_in[21];
    const float* Wtb  = (const float*)d_in[22]; const float* btb  = (const float*)d_in[23];
    const float* Wbt  = (const float*)d_in[24]; const float* bbt  = (const float*)d_in[25];

    float* ws = (float*)d_ws;
    size_t o = 0;
    auto take = [&](size_t n) { float* p = ws + o; o += n; return p; };
    float* XGF    = take(SEQ * G);
    float* XGB    = take(SEQ * G);
    float* WHLT   = take(D * G);
    float* WHRT   = take(D * G);
    float* WORDIN = take(SEQ * 2 * D);
    float* TW     = take(SEQ * D);
    float* BW     = take(SEQ * D);
    float* RVb    = take(NREL * D);
    float* EVb    = take(NENT * D);
    float* WTWT   = take(2 * D * D);
    float* WTRT   = take(D * D);
    float* WTMT   = take(D * D);
    float* WBWT   = take(2 * D * D);
    float* WBET   = take(D * D);
    float* WBMT   = take(D * D);
    float* WBGT   = take(D * D);
    float* WTTT   = take(D * D);
    float* WTBT   = take(D * D);
    float* WBTT   = take(D * D);

    auto tr = [&](const float* in, float* outp, int rows, int cols, int stride, int off) {
        int n = rows * cols;
        k_trans<<<(n + 255) / 256, 256, 0, stream>>>(in, outp, rows, cols, stride, off);
    };
    tr(WhhL, WHLT, G, D, D, 0);          // WHLT[k*G + j] = WhhL[j][k]
    tr(WhhR, WHRT, G, D, D, 0);
    tr(Wt,  WTWT, D, 2 * D, G, 0);       // WTWT[j*D + i] = Wt[i][j], j<512
    tr(Wt,  WTRT, D, D, G, 512);
    tr(Wt,  WTMT, D, D, G, 768);
    tr(Wb,  WBWT, D, 2 * D, 5 * D, 0);   // Wb stride 1280
    tr(Wb,  WBET, D, D, 5 * D, 512);
    tr(Wb,  WBMT, D, D, 5 * D, 768);
    tr(Wb,  WBGT, D, D, 5 * D, 1024);
    tr(Wtt, WTTT, D, D, D, 0);
    tr(Wtb, WTBT, D, D, D, 0);
    tr(Wbt, WBTT, D, D, D, 0);

    k_xg<<<SEQ, 1024, 0, stream>>>(text, wordvector, WihL, bihL, bhhL, XGF);
    k_xg<<<SEQ, 1024, 0, stream>>>(text, wordvector, WihR, bihR, bhhR, XGB);
    k_lstm<<<2, 1024, 0, stream>>>(XGF, XGB, WHLT, WHRT, WORDIN);
    k_prep2<<<SEQ + NREL + NENT, 256, 0, stream>>>(WORDIN, WTWT, WBWT, WTRT, WBET,
                                                   relvec, entvec, bt, bb,
                                                   TW, BW, RVb, EVb);
    k_main<<<1, 256, 0, stream>>>(TW, BW, RVb, EVb, WTMT, WTTT, WTBT, WBTT,
                                  WBMT, WBGT, Wp, bp, Wpl, bpl, btt, btb, bbt,
                                  (float*)d_out);
}

// Round 2
// 61994.299 us; speedup vs baseline: 1.2339x; 1.2339x over previous
//
#include <hip/hip_runtime.h>
#include <float.h>

constexpr int SEQ  = 128;   // sentence length T
constexpr int D    = 256;   // DIM / STATEDIM
constexpr int G    = 1024;  // 4*DIM gate width
constexpr int NREL = 26;    // REL_COUNT + 1
constexpr int NENT = 7;

// ---------------------------------------------------------------------------
// Generic strided transpose: out[k*rows + i] = in[i*in_stride + in_off + k]
// ---------------------------------------------------------------------------
__global__ void k_trans(const float* __restrict__ in, float* __restrict__ out,
                        int rows, int cols, int in_stride, int in_off)
{
    int idx = blockIdx.x * 256 + threadIdx.x;
    if (idx >= rows * cols) return;
    int i = idx % rows;
    int k = idx / rows;
    out[idx] = in[(size_t)i * in_stride + in_off + k];
}

// ---------------------------------------------------------------------------
// xg[t][j] = bih[j] + bhh[j] + sum_k wordvector[text[t]][k] * Wih[j][k]
// ---------------------------------------------------------------------------
__global__ __launch_bounds__(1024) void k_xg(
    const int* __restrict__ text, const float* __restrict__ wv,
    const float* __restrict__ Wih, const float* __restrict__ bih,
    const float* __restrict__ bhh, float* __restrict__ xg)
{
    int t = blockIdx.x, j = threadIdx.x;
    const float* x  = wv + (size_t)text[t] * D;
    const float* wr = Wih + (size_t)j * D;
    float acc = bih[j] + bhh[j];
    for (int k = 0; k < D; ++k) acc += x[k] * wr[k];
    xg[t * G + j] = acc;
}

// ---------------------------------------------------------------------------
// Sequential LSTM, one block per direction (grid=2), 1024 threads.
// ---------------------------------------------------------------------------
__global__ __launch_bounds__(1024) void k_lstm(
    const float* __restrict__ xgF, const float* __restrict__ xgB,
    const float* __restrict__ WHTF, const float* __restrict__ WHTB,
    float* __restrict__ wordin)
{
    int dir = blockIdx.x;
    const float* xg  = dir ? xgB  : xgF;
    const float* WHT = dir ? WHTB : WHTF;
    __shared__ float h[D], c[D], g[G];
    int j = threadIdx.x;
    if (j < D) { h[j] = 0.f; c[j] = 0.f; }
    __syncthreads();
    for (int s = 0; s < SEQ; ++s) {
        int t = dir ? (SEQ - 1 - s) : s;
        float acc = xg[t * G + j];
        for (int k = 0; k < D; ++k) acc += WHT[k * G + j] * h[k];
        g[j] = acc;
        __syncthreads();
        if (j < D) {
            float si = 1.f / (1.f + expf(-g[j]));
            float sf = 1.f / (1.f + expf(-g[D + j]));
            float gg = tanhf(g[2 * D + j]);
            float so = 1.f / (1.f + expf(-g[3 * D + j]));
            float cn = sf * c[j] + si * gg;
            float hn = so * tanhf(cn);
            c[j] = cn; h[j] = hn;
            wordin[t * (2 * D) + dir * D + j] = hn;
        }
        __syncthreads();
    }
}

// ---------------------------------------------------------------------------
// Parallel precompute after LSTM (TW/BW per word, RV per relation, EV per ent)
// ---------------------------------------------------------------------------
__global__ __launch_bounds__(256) void k_prep2(
    const float* __restrict__ wordin,
    const float* __restrict__ WTWT, const float* __restrict__ WBWT,
    const float* __restrict__ WTRT, const float* __restrict__ WBET,
    const float* __restrict__ relvec, const float* __restrict__ entvec,
    const float* __restrict__ btv, const float* __restrict__ bbv,
    float* __restrict__ TW, float* __restrict__ BW,
    float* __restrict__ RV, float* __restrict__ EV)
{
    int b = blockIdx.x, i = threadIdx.x;
    if (b < SEQ) {
        const float* w = wordin + b * (2 * D);
        float a1 = btv[i], a2 = bbv[i];
        for (int j = 0; j < 2 * D; ++j) {
            float wv = w[j];
            a1 += wv * WTWT[j * D + i];
            a2 += wv * WBWT[j * D + i];
        }
        TW[b * D + i] = a1;
        BW[b * D + i] = a2;
    } else if (b < SEQ + NREL) {
        int r = b - SEQ;
        const float* x = relvec + r * D;
        float a = 0.f;
        for (int k = 0; k < D; ++k) a += x[k] * WTRT[k * D + i];
        RV[r * D + i] = a;
    } else {
        int e = b - SEQ - NREL;
        const float* x = entvec + e * D;
        float a = 0.f;
        for (int k = 0; k < D; ++k) a += x[k] * WBET[k * D + i];
        EV[e * D + i] = a;
    }
}

// ---------------------------------------------------------------------------
// M1T[j*D + i] = sum_k WBGT[k*D+i] * Wtt[k*D+j]   (M1 = Wb_target @ Wtt)
// ---------------------------------------------------------------------------
__global__ __launch_bounds__(256) void k_m1(
    const float* __restrict__ WBGT, const float* __restrict__ Wtt,
    float* __restrict__ M1T)
{
    int j = blockIdx.x, i = threadIdx.x;
    float a = 0.f;
    for (int k = 0; k < D; ++k) a = fmaf(WBGT[k * D + i], Wtt[k * D + j], a);
    M1T[j * D + i] = a;
}

// c1[i] = sum_k WBGT[k*D+i] * btt[k]
__global__ __launch_bounds__(256) void k_c1(
    const float* __restrict__ WBGT, const float* __restrict__ btt,
    float* __restrict__ c1)
{
    int i = threadIdx.x;
    float a = 0.f;
    for (int k = 0; k < D; ++k) a = fmaf(WBGT[k * D + i], btt[k], a);
    c1[i] = a;
}

// ---------------------------------------------------------------------------
// Per-thread-contiguous pack of Wb_m for the register-resident bot matvec:
// WB2[tid*128 + kk] = Wb[i][768 + h*128 + kk],  tid = h*256+i
// ---------------------------------------------------------------------------
__global__ __launch_bounds__(256) void k_pack(
    const float* __restrict__ Wb, float* __restrict__ WB2)
{
    int e = blockIdx.x * 256 + threadIdx.x;      // 0..65535
    int tid = e >> 7, kk = e & 127;
    int h = tid >> 8, i = tid & 255;
    WB2[e] = Wb[(size_t)i * (5 * D) + 3 * D + h * 128 + kk];
}

// ---------------------------------------------------------------------------
// Streamed split-k half-matvec: Wcol points at W^T[k0*D + i] (k-major),
// x points at the LDS vector slice for this k-half. 4 independent chains.
// ---------------------------------------------------------------------------
__device__ inline float mv_half(const float* __restrict__ Wcol,
                                const float* __restrict__ x)
{
    float a0 = 0.f, a1 = 0.f, a2 = 0.f, a3 = 0.f;
    #pragma unroll
    for (int kk = 0; kk < 128; kk += 4) {
        a0 = fmaf(Wcol[(kk + 0) * D], x[kk + 0], a0);
        a1 = fmaf(Wcol[(kk + 1) * D], x[kk + 1], a1);
        a2 = fmaf(Wcol[(kk + 2) * D], x[kk + 2], a2);
        a3 = fmaf(Wcol[(kk + 3) * D], x[kk + 3], a3);
    }
    return (a0 + a1) + (a2 + a3);
}

// ---------------------------------------------------------------------------
// Softmax + first-occurrence argmax over n values living in lanes 0..n-1 of
// each W-lane group. Mimics reference: p = exp(l-max)/sum, argmax over p.
// Lanes >= n pass lv = -FLT_MAX. Result (am) is wave-uniform (ballot-based);
// spurious ballot bits from other groups are all >= W so ffsll stays correct.
// ---------------------------------------------------------------------------
template<int W>
__device__ inline void grp_smax(float lv, int n, int lane, int& am, float& pm)
{
    float mx = lv;
    #pragma unroll
    for (int off = W / 2; off; off >>= 1) mx = fmaxf(mx, __shfl_xor(mx, off));
    float e  = (lane < n) ? expf(lv - mx) : 0.f;
    float se = e;
    #pragma unroll
    for (int off = W / 2; off; off >>= 1) se += __shfl_xor(se, off);
    float p  = (lane < n) ? (e / se) : -1.f;
    float q  = p;
    #pragma unroll
    for (int off = W / 2; off; off >>= 1) q = fmaxf(q, __shfl_xor(q, off));
    unsigned long long mask = __ballot(p == q);
    am = __ffsll((long long)mask) - 1;
    pm = q;
}

// ---------------------------------------------------------------------------
// Sequential main kernel: 1 block, 512 threads (8 waves, 2/SIMD).
// Thread tid: output i = tid&255, k-half h = tid>>8.
// W_bm half-column (128 floats) lives in 32 float4 registers per thread.
// 2 barriers per bot step; softmax/argmax redundantly per wave (uniform reg).
// ---------------------------------------------------------------------------
__global__ __launch_bounds__(512) void k_main2(
    const float* __restrict__ TW,   const float* __restrict__ BW,
    const float* __restrict__ RV,   const float* __restrict__ EV,
    const float* __restrict__ WTMT, const float* __restrict__ WTBT,
    const float* __restrict__ WBTT, const float* __restrict__ M1T,
    const float* __restrict__ c1v,  const float* __restrict__ WB2,
    const float* __restrict__ Wp,   const float* __restrict__ bp,
    const float* __restrict__ Wpl,  const float* __restrict__ bpl,
    const float* __restrict__ btb,  const float* __restrict__ bbt,
    float* __restrict__ out)
{
    const int tid  = threadIdx.x;
    const int lane = tid & 63;
    const int wv   = tid >> 6;        // wave id 0..7
    const int h    = tid >> 8;        // k-half
    const int i    = tid & 255;       // output index
    const bool lower = (tid < 256);

    __shared__ __align__(16) float xbuf[2][D];
    __shared__ __align__(16) float pbuf[D], pbufB[D], pbufC[D];
    __shared__ __align__(16) float mem[D], outv[D];
    __shared__ __align__(16) float Esh[NENT * D], WrSh[NENT * D];
    __shared__ float lpart[4][32];
    __shared__ float brSh[8];

    // register-resident W_bm half-column (coalesced-per-thread packed layout)
    float4 wb[32];
    {
        const float4* src = reinterpret_cast<const float4*>(WB2) + tid * 32;
        #pragma unroll
        for (int q = 0; q < 32; ++q) wb[q] = src[q];
    }
    for (int k = tid; k < NENT * D; k += 512) Esh[k] = EV[k];
    if (lower) mem[i] = 0.f;
    __syncthreads();

    const float* WTMh = WTMT + (size_t)h * 128 * D + i;
    const float* WTBh = WTBT + (size_t)h * 128 * D + i;
    const float* WBTh = WBTT + (size_t)h * 128 * D + i;
    const float* M1h  = M1T  + (size_t)h * 128 * D + i;

    int rel = 0;

    for (int t = 0; t < SEQ; ++t) {
        // ---- top step: outp = tanh(TW[t] + RV[rel] + Wt_m @ mem) ----
        float a = mv_half(WTMh, mem + h * 128);
        if (!lower) pbuf[i] = a;
        __syncthreads();
        if (lower) {
            float tot  = a + pbuf[i] + TW[t * D + i] + RV[rel * D + i];
            float outp = tanhf(tot);
            outv[i] = outp;
            #pragma unroll
            for (int r = 0; r < NREL; ++r) {
                float pp = outp * Wp[r * D + i];
                #pragma unroll
                for (int off = 32; off; off >>= 1) pp += __shfl_xor(pp, off);
                if (lane == 0) lpart[wv][r] = pp;
            }
        }
        __syncthreads();
        float lv = -FLT_MAX;
        if (lane < NREL)
            lv = lpart[0][lane] + lpart[1][lane] + lpart[2][lane] +
                 lpart[3][lane] + bp[lane];
        int am; float pm;
        grp_smax<32>(lv, NREL, lane, am, pm);
        if (tid == 0) { out[t] = (float)am; out[SEQ + t] = pm; }
        const int action = am;   // wave-uniform

        if (action > 0) {
            rel = action;
            // memb0 = Wtb@outp + btb ;  btm = M1@outp + c1  (tgt folded away)
            float bs = mv_half(WTBh, outv + h * 128);
            float cs = mv_half(M1h,  outv + h * 128);
            if (!lower) { pbufB[i] = bs; pbufC[i] = cs; }
            const size_t wbase = (size_t)(action - 1) * NENT * D;
            for (int k = tid; k < NENT * D; k += 512) WrSh[k] = Wpl[wbase + k];
            if (tid < NENT) brSh[tid] = bpl[(action - 1) * NENT + tid];
            __syncthreads();
            float btm = 0.f;
            if (lower) {
                xbuf[0][i] = bs + pbufB[i] + btb[i];
                btm = cs + pbufC[i] + c1v[i];
            }
            __syncthreads();

            int p = 0, ab = 0;
            for (int s = 0; s < SEQ; ++s) {
                // -- matvec W_bm @ x from registers (x broadcast from LDS) --
                const float4* xb =
                    reinterpret_cast<const float4*>(xbuf[p] + h * 128);
                float m0 = 0.f, m1 = 0.f, m2 = 0.f, m3 = 0.f;
                #pragma unroll
                for (int q = 0; q < 32; q += 4) {
                    float4 x0 = xb[q], x1 = xb[q + 1], x2 = xb[q + 2], x3 = xb[q + 3];
                    m0 = fmaf(wb[q].x,     x0.x, m0); m0 = fmaf(wb[q].y,     x0.y, m0);
                    m0 = fmaf(wb[q].z,     x0.z, m0); m0 = fmaf(wb[q].w,     x0.w, m0);
                    m1 = fmaf(wb[q + 1].x, x1.x, m1); m1 = fmaf(wb[q + 1].y, x1.y, m1);
                    m1 = fmaf(wb[q + 1].z, x1.z, m1); m1 = fmaf(wb[q + 1].w, x1.w, m1);
                    m2 = fmaf(wb[q + 2].x, x2.x, m2); m2 = fmaf(wb[q + 2].y, x2.y, m2);
                    m2 = fmaf(wb[q + 2].z, x2.z, m2); m2 = fmaf(wb[q + 2].w, x2.w, m2);
                    m3 = fmaf(wb[q + 3].x, x3.x, m3); m3 = fmaf(wb[q + 3].y, x3.y, m3);
                    m3 = fmaf(wb[q + 3].z, x3.z, m3); m3 = fmaf(wb[q + 3].w, x3.w, m3);
                }
                float ms = (m0 + m1) + (m2 + m3);
                if (!lower) pbuf[i] = ms;
                __syncthreads();                       // barrier 1
                if (lower) {
                    float tot = ms + pbuf[i] + BW[s * D + i] +
                                Esh[ab * D + i] + btm;
                    float ob = tanhf(tot);
                    xbuf[p ^ 1][i] = ob;
                    #pragma unroll
                    for (int r = 0; r < NENT; ++r) {
                        float pp = ob * WrSh[r * D + i];
                        #pragma unroll
                        for (int off = 32; off; off >>= 1)
                            pp += __shfl_xor(pp, off);
                        if (lane == 0) lpart[wv][r] = pp;
                    }
                }
                __syncthreads();                       // barrier 2
                float lv2 = -FLT_MAX;
                if (lane < NENT)
                    lv2 = lpart[0][lane] + lpart[1][lane] + lpart[2][lane] +
                          lpart[3][lane] + brSh[lane];
                int am2; float pm2;
                grp_smax<8>(lv2, NENT, lane, am2, pm2);
                if (tid == 0) {
                    out[2 * SEQ + t * SEQ + s] = (float)am2;
                    out[2 * SEQ + SEQ * SEQ + t * SEQ + s] = pm2;
                }
                ab = am2;        // wave-uniform register, no LDS roundtrip
                p ^= 1;
            }
            // mem = Wbt @ membf + bbt
            float es = mv_half(WBTh, xbuf[p] + h * 128);
            if (!lower) pbuf[i] = es;
            __syncthreads();
            if (lower) mem[i] = es + pbuf[i] + bbt[i];
            __syncthreads();
        } else {
            if (lower) mem[i] = outv[i];
            if (tid < SEQ) {
                out[2 * SEQ + t * SEQ + tid] = 0.f;
                out[2 * SEQ + SEQ * SEQ + t * SEQ + tid] = 0.f;
            }
            __syncthreads();
        }
    }
}

// ---------------------------------------------------------------------------
extern "C" void kernel_launch(void* const* d_in, const int* in_sizes, int n_in,
                              void* d_out, int out_size, void* d_ws, size_t ws_size,
                              hipStream_t stream)
{
    (void)in_sizes; (void)n_in; (void)out_size; (void)ws_size;
    const int*   text       = (const int*)  d_in[0];
    const float* wordvector = (const float*)d_in[1];
    const float* relvec     = (const float*)d_in[2];
    const float* entvec     = (const float*)d_in[3];
    const float* WihL = (const float*)d_in[4];  const float* WhhL = (const float*)d_in[5];
    const float* bihL = (const float*)d_in[6];  const float* bhhL = (const float*)d_in[7];
    const float* WihR = (const float*)d_in[8];  const float* WhhR = (const float*)d_in[9];
    const float* bihR = (const float*)d_in[10]; const float* bhhR = (const float*)d_in[11];
    const float* Wt   = (const float*)d_in[12]; const float* bt   = (const float*)d_in[13];
    const float* Wp   = (const float*)d_in[14]; const float* bp   = (const float*)d_in[15];
    const float* Wb   = (const float*)d_in[16]; const float* bb   = (const float*)d_in[17];
    const float* Wpl  = (const float*)d_in[18]; const float* bpl  = (const float*)d_in[19];
    const float* Wtt  = (const float*)d_in[20]; const float* btt  = (const float*)d_in[21];
    const float* Wtb  = (const float*)d_in[22]; const float* btb  = (const float*)d_in[23];
    const float* Wbt  = (const float*)d_in[24]; const float* bbt  = (const float*)d_in[25];

    float* ws = (float*)d_ws;
    size_t o = 0;
    auto take = [&](size_t n) { float* p = ws + o; o += n; return p; };
    float* XGF    = take(SEQ * G);
    float* XGB    = take(SEQ * G);
    float* WHLT   = take(D * G);
    float* WHRT   = take(D * G);
    float* WORDIN = take(SEQ * 2 * D);
    float* TW     = take(SEQ * D);
    float* BW     = take(SEQ * D);
    float* RVb    = take(NREL * D);
    float* EVb    = take(NENT * D);
    float* WTWT   = take(2 * D * D);
    float* WTRT   = take(D * D);
    float* WTMT   = take(D * D);
    float* WBWT   = take(2 * D * D);
    float* WBET   = take(D * D);
    float* WBGT   = take(D * D);
    float* WTBT   = take(D * D);
    float* WBTT   = take(D * D);
    float* M1T    = take(D * D);
    float* C1     = take(D);
    float* WB2    = take(2 * 128 * D);   // 512 threads * 128 floats

    auto tr = [&](const float* in, float* outp, int rows, int cols, int stride, int off) {
        int n = rows * cols;
        k_trans<<<(n + 255) / 256, 256, 0, stream>>>(in, outp, rows, cols, stride, off);
    };
    tr(WhhL, WHLT, G, D, D, 0);          // WHLT[k*G + j] = WhhL[j][k]
    tr(WhhR, WHRT, G, D, D, 0);
    tr(Wt,  WTWT, D, 2 * D, G, 0);       // word part of Wt
    tr(Wt,  WTRT, D, D, G, 512);         // relvec part
    tr(Wt,  WTMT, D, D, G, 768);         // mem part
    tr(Wb,  WBWT, D, 2 * D, 5 * D, 0);   // word part of Wb
    tr(Wb,  WBET, D, D, 5 * D, 512);     // entvec part
    tr(Wb,  WBGT, D, D, 5 * D, 1024);    // target part (feeds M1/c1)
    tr(Wtb, WTBT, D, D, D, 0);
    tr(Wbt, WBTT, D, D, D, 0);

    k_m1<<<D, D, 0, stream>>>(WBGT, Wtt, M1T);
    k_c1<<<1, D, 0, stream>>>(WBGT, btt, C1);
    k_pack<<<256, 256, 0, stream>>>(Wb, WB2);

    k_xg<<<SEQ, 1024, 0, stream>>>(text, wordvector, WihL, bihL, bhhL, XGF);
    k_xg<<<SEQ, 1024, 0, stream>>>(text, wordvector, WihR, bihR, bhhR, XGB);
    k_lstm<<<2, 1024, 0, stream>>>(XGF, XGB, WHLT, WHRT, WORDIN);
    k_prep2<<<SEQ + NREL + NENT, 256, 0, stream>>>(WORDIN, WTWT, WBWT, WTRT, WBET,
                                                   relvec, entvec, bt, bb,
                                                   TW, BW, RVb, EVb);
    k_main2<<<1, 512, 0, stream>>>(TW, BW, RVb, EVb, WTMT, WTBT, WBTT, M1T, C1,
                                   WB2, Wp, bp, Wpl, bpl, btb, bbt,
                                   (float*)d_out);
}

// Round 3
// 60780.463 us; speedup vs baseline: 1.2586x; 1.0200x over previous
//
#include <hip/hip_runtime.h>
#include <float.h>

constexpr int SEQ  = 128;   // sentence length T
constexpr int D    = 256;   // DIM / STATEDIM
constexpr int G    = 1024;  // 4*DIM gate width
constexpr int NREL = 26;    // REL_COUNT + 1
constexpr int NENT = 7;

typedef float v2f __attribute__((ext_vector_type(2)));

// ---------------------------------------------------------------------------
// Generic strided transpose: out[k*rows + i] = in[i*in_stride + in_off + k]
// ---------------------------------------------------------------------------
__global__ void k_trans(const float* __restrict__ in, float* __restrict__ out,
                        int rows, int cols, int in_stride, int in_off)
{
    int idx = blockIdx.x * 256 + threadIdx.x;
    if (idx >= rows * cols) return;
    int i = idx % rows;
    int k = idx / rows;
    out[idx] = in[(size_t)i * in_stride + in_off + k];
}

// ---------------------------------------------------------------------------
// xg[t][j] = bih[j] + bhh[j] + sum_k wordvector[text[t]][k] * Wih[j][k]
// ---------------------------------------------------------------------------
__global__ __launch_bounds__(1024) void k_xg(
    const int* __restrict__ text, const float* __restrict__ wv,
    const float* __restrict__ Wih, const float* __restrict__ bih,
    const float* __restrict__ bhh, float* __restrict__ xg)
{
    int t = blockIdx.x, j = threadIdx.x;
    const float* x  = wv + (size_t)text[t] * D;
    const float* wr = Wih + (size_t)j * D;
    float acc = bih[j] + bhh[j];
    for (int k = 0; k < D; ++k) acc += x[k] * wr[k];
    xg[t * G + j] = acc;
}

// ---------------------------------------------------------------------------
// Sequential LSTM, one block per direction (grid=2), 1024 threads.
// ---------------------------------------------------------------------------
__global__ __launch_bounds__(1024) void k_lstm(
    const float* __restrict__ xgF, const float* __restrict__ xgB,
    const float* __restrict__ WHTF, const float* __restrict__ WHTB,
    float* __restrict__ wordin)
{
    int dir = blockIdx.x;
    const float* xg  = dir ? xgB  : xgF;
    const float* WHT = dir ? WHTB : WHTF;
    __shared__ float h[D], c[D], g[G];
    int j = threadIdx.x;
    if (j < D) { h[j] = 0.f; c[j] = 0.f; }
    __syncthreads();
    for (int s = 0; s < SEQ; ++s) {
        int t = dir ? (SEQ - 1 - s) : s;
        float acc = xg[t * G + j];
        for (int k = 0; k < D; ++k) acc += WHT[k * G + j] * h[k];
        g[j] = acc;
        __syncthreads();
        if (j < D) {
            float si = 1.f / (1.f + expf(-g[j]));
            float sf = 1.f / (1.f + expf(-g[D + j]));
            float gg = tanhf(g[2 * D + j]);
            float so = 1.f / (1.f + expf(-g[3 * D + j]));
            float cn = sf * c[j] + si * gg;
            float hn = so * tanhf(cn);
            c[j] = cn; h[j] = hn;
            wordin[t * (2 * D) + dir * D + j] = hn;
        }
        __syncthreads();
    }
}

// ---------------------------------------------------------------------------
// Parallel precompute after LSTM (TW/BW per word, RV per relation, EV per ent)
// ---------------------------------------------------------------------------
__global__ __launch_bounds__(256) void k_prep2(
    const float* __restrict__ wordin,
    const float* __restrict__ WTWT, const float* __restrict__ WBWT,
    const float* __restrict__ WTRT, const float* __restrict__ WBET,
    const float* __restrict__ relvec, const float* __restrict__ entvec,
    const float* __restrict__ btv, const float* __restrict__ bbv,
    float* __restrict__ TW, float* __restrict__ BW,
    float* __restrict__ RV, float* __restrict__ EV)
{
    int b = blockIdx.x, i = threadIdx.x;
    if (b < SEQ) {
        const float* w = wordin + b * (2 * D);
        float a1 = btv[i], a2 = bbv[i];
        for (int j = 0; j < 2 * D; ++j) {
            float wv = w[j];
            a1 += wv * WTWT[j * D + i];
            a2 += wv * WBWT[j * D + i];
        }
        TW[b * D + i] = a1;
        BW[b * D + i] = a2;
    } else if (b < SEQ + NREL) {
        int r = b - SEQ;
        const float* x = relvec + r * D;
        float a = 0.f;
        for (int k = 0; k < D; ++k) a += x[k] * WTRT[k * D + i];
        RV[r * D + i] = a;
    } else {
        int e = b - SEQ - NREL;
        const float* x = entvec + e * D;
        float a = 0.f;
        for (int k = 0; k < D; ++k) a += x[k] * WBET[k * D + i];
        EV[e * D + i] = a;
    }
}

// ---------------------------------------------------------------------------
// M1T[j*D + i] = sum_k WBGT[k*D+i] * Wtt[k*D+j]   (M1 = Wb_target @ Wtt)
// ---------------------------------------------------------------------------
__global__ __launch_bounds__(256) void k_m1(
    const float* __restrict__ WBGT, const float* __restrict__ Wtt,
    float* __restrict__ M1T)
{
    int j = blockIdx.x, i = threadIdx.x;
    float a = 0.f;
    for (int k = 0; k < D; ++k) a = fmaf(WBGT[k * D + i], Wtt[k * D + j], a);
    M1T[j * D + i] = a;
}

// c1[i] = sum_k WBGT[k*D+i] * btt[k]
__global__ __launch_bounds__(256) void k_c1(
    const float* __restrict__ WBGT, const float* __restrict__ btt,
    float* __restrict__ c1)
{
    int i = threadIdx.x;
    float a = 0.f;
    for (int k = 0; k < D; ++k) a = fmaf(WBGT[k * D + i], btt[k], a);
    c1[i] = a;
}

// ---------------------------------------------------------------------------
// Per-thread-contiguous pack of Wb_m for the register-resident bot matvec:
// WB2[tid*128 + kk] = Wb[i][768 + h*128 + kk],  tid = h*256+i
// ---------------------------------------------------------------------------
__global__ __launch_bounds__(256) void k_pack(
    const float* __restrict__ Wb, float* __restrict__ WB2)
{
    int e = blockIdx.x * 256 + threadIdx.x;      // 0..65535
    int tid = e >> 7, kk = e & 127;
    int h = tid >> 8, i = tid & 255;
    WB2[e] = Wb[(size_t)i * (5 * D) + 3 * D + h * 128 + kk];
}

// ---------------------------------------------------------------------------
// Streamed split-k half-matvec: Wcol points at W^T[k0*D + i] (k-major),
// x points at the LDS vector slice for this k-half. 4 independent chains.
// ---------------------------------------------------------------------------
__device__ inline float mv_half(const float* __restrict__ Wcol,
                                const float* __restrict__ x)
{
    float a0 = 0.f, a1 = 0.f, a2 = 0.f, a3 = 0.f;
    #pragma unroll
    for (int kk = 0; kk < 128; kk += 4) {
        a0 = fmaf(Wcol[(kk + 0) * D], x[kk + 0], a0);
        a1 = fmaf(Wcol[(kk + 1) * D], x[kk + 1], a1);
        a2 = fmaf(Wcol[(kk + 2) * D], x[kk + 2], a2);
        a3 = fmaf(Wcol[(kk + 3) * D], x[kk + 3], a3);
    }
    return (a0 + a1) + (a2 + a3);
}

// ---------------------------------------------------------------------------
// Softmax + first-occurrence argmax over n values living in lanes 0..n-1 of
// each W-lane group. Mimics reference: p = exp(l-max)/sum, argmax over p.
// Lanes >= n pass lv = -FLT_MAX. Result (am) is wave-uniform (ballot-based);
// spurious ballot bits from other groups are all >= W so ffsll stays correct.
// ---------------------------------------------------------------------------
template<int W>
__device__ inline void grp_smax(float lv, int n, int lane, int& am, float& pm)
{
    float mx = lv;
    #pragma unroll
    for (int off = W / 2; off; off >>= 1) mx = fmaxf(mx, __shfl_xor(mx, off));
    float e  = (lane < n) ? expf(lv - mx) : 0.f;
    float se = e;
    #pragma unroll
    for (int off = W / 2; off; off >>= 1) se += __shfl_xor(se, off);
    float p  = (lane < n) ? (e / se) : -1.f;
    float q  = p;
    #pragma unroll
    for (int off = W / 2; off; off >>= 1) q = fmaxf(q, __shfl_xor(q, off));
    unsigned long long mask = __ballot(p == q);
    am = __ffsll((long long)mask) - 1;
    pm = q;
}

// ---------------------------------------------------------------------------
// Sequential main kernel: 1 block, 512 threads = 8 waves = 2 waves/SIMD.
// __launch_bounds__(512, 2) -> 256-VGPR budget so the 128-reg weight block
// stays register-resident (R1 failure: default budget 128 -> full spill).
// Thread tid: output i = tid&255, k-half h = tid>>8.
// Inner matvec uses packed f32 FMA (v_pk_fma_f32): 64 VALU instr/thread.
// ---------------------------------------------------------------------------
__global__ __launch_bounds__(512, 2) void k_main2(
    const float* __restrict__ TW,   const float* __restrict__ BW,
    const float* __restrict__ RV,   const float* __restrict__ EV,
    const float* __restrict__ WTMT, const float* __restrict__ WTBT,
    const float* __restrict__ WBTT, const float* __restrict__ M1T,
    const float* __restrict__ c1v,  const float* __restrict__ WB2,
    const float* __restrict__ Wp,   const float* __restrict__ bp,
    const float* __restrict__ Wpl,  const float* __restrict__ bpl,
    const float* __restrict__ btb,  const float* __restrict__ bbt,
    float* __restrict__ out)
{
    const int tid  = threadIdx.x;
    const int lane = tid & 63;
    const int wv   = tid >> 6;        // wave id 0..7
    const int h    = tid >> 8;        // k-half
    const int i    = tid & 255;       // output index
    const bool lower = (tid < 256);

    __shared__ __align__(16) float xbuf[2][D];
    __shared__ __align__(16) float pbuf[D], pbufB[D], pbufC[D];
    __shared__ __align__(16) float mem[D], outv[D];
    __shared__ __align__(16) float WrSh[NENT * D];
    __shared__ float lpart[4][32];
    __shared__ float brSh[8];

    // register-resident W_bm half-column (per-thread contiguous pack)
    v2f w2[64];
    {
        const v2f* src = reinterpret_cast<const v2f*>(WB2) + tid * 64;
        #pragma unroll
        for (int q = 0; q < 64; ++q) w2[q] = src[q];
    }
    // loop-invariant entity columns, register-resident (lower half only)
    float ev0 = 0.f, ev1 = 0.f, ev2 = 0.f, ev3 = 0.f,
          ev4 = 0.f, ev5 = 0.f, ev6 = 0.f;
    if (lower) {
        ev0 = EV[0 * D + i]; ev1 = EV[1 * D + i]; ev2 = EV[2 * D + i];
        ev3 = EV[3 * D + i]; ev4 = EV[4 * D + i]; ev5 = EV[5 * D + i];
        ev6 = EV[6 * D + i];
        mem[i] = 0.f;
    }
    __syncthreads();

    const float* WTMh = WTMT + (size_t)h * 128 * D + i;
    const float* WTBh = WTBT + (size_t)h * 128 * D + i;
    const float* WBTh = WBTT + (size_t)h * 128 * D + i;
    const float* M1h  = M1T  + (size_t)h * 128 * D + i;

    int rel = 0;

    for (int t = 0; t < SEQ; ++t) {
        // ---- top step: outp = tanh(TW[t] + RV[rel] + Wt_m @ mem) ----
        float a = mv_half(WTMh, mem + h * 128);
        if (!lower) pbuf[i] = a;
        __syncthreads();
        if (lower) {
            float tot  = a + pbuf[i] + TW[t * D + i] + RV[rel * D + i];
            float outp = tanhf(tot);
            outv[i] = outp;
            #pragma unroll
            for (int r = 0; r < NREL; ++r) {
                float pp = outp * Wp[r * D + i];
                #pragma unroll
                for (int off = 32; off; off >>= 1) pp += __shfl_xor(pp, off);
                if (lane == 0) lpart[wv][r] = pp;
            }
        }
        __syncthreads();
        float lv = -FLT_MAX;
        if (lane < NREL)
            lv = lpart[0][lane] + lpart[1][lane] + lpart[2][lane] +
                 lpart[3][lane] + bp[lane];
        int am; float pm;
        grp_smax<32>(lv, NREL, lane, am, pm);
        if (tid == 0) { out[t] = (float)am; out[SEQ + t] = pm; }
        const int action = am;   // wave-uniform

        if (action > 0) {
            rel = action;
            // memb0 = Wtb@outp + btb ;  btm = M1@outp + c1  (tgt folded away)
            float bs = mv_half(WTBh, outv + h * 128);
            float cs = mv_half(M1h,  outv + h * 128);
            if (!lower) { pbufB[i] = bs; pbufC[i] = cs; }
            const size_t wbase = (size_t)(action - 1) * NENT * D;
            for (int k = tid; k < NENT * D; k += 512) WrSh[k] = Wpl[wbase + k];
            if (tid < NENT) brSh[tid] = bpl[(action - 1) * NENT + tid];
            __syncthreads();
            float btm = 0.f, bwc = 0.f;
            if (lower) {
                xbuf[0][i] = bs + pbufB[i] + btb[i];
                btm = cs + pbufC[i] + c1v[i];
                bwc = BW[i];          // prefetch BW row 0
            }
            __syncthreads();

            int p = 0, ab = 0;
            for (int s = 0; s < SEQ; ++s) {
                // -- matvec W_bm @ x: packed f32 FMA from registers --
                const float4* xb =
                    reinterpret_cast<const float4*>(xbuf[p] + h * 128);
                v2f A0 = {0.f, 0.f}, A1 = {0.f, 0.f},
                    A2 = {0.f, 0.f}, A3 = {0.f, 0.f};
                #pragma unroll
                for (int q = 0; q < 32; q += 2) {
                    float4 x0 = xb[q], x1 = xb[q + 1];
                    v2f xa = {x0.x, x0.y}, xc = {x0.z, x0.w};
                    v2f xd = {x1.x, x1.y}, xe = {x1.z, x1.w};
                    A0 = __builtin_elementwise_fma(w2[2 * q + 0], xa, A0);
                    A1 = __builtin_elementwise_fma(w2[2 * q + 1], xc, A1);
                    A2 = __builtin_elementwise_fma(w2[2 * q + 2], xd, A2);
                    A3 = __builtin_elementwise_fma(w2[2 * q + 3], xe, A3);
                }
                float ms = ((A0.x + A0.y) + (A1.x + A1.y)) +
                           ((A2.x + A2.y) + (A3.x + A3.y));
                if (!lower) pbuf[i] = ms;
                __syncthreads();                       // barrier 1
                if (lower) {
                    float ev = (ab == 0) ? ev0 : (ab == 1) ? ev1 :
                               (ab == 2) ? ev2 : (ab == 3) ? ev3 :
                               (ab == 4) ? ev4 : (ab == 5) ? ev5 : ev6;
                    float tot = ms + pbuf[i] + bwc + ev + btm;
                    float ob = tanhf(tot);
                    xbuf[p ^ 1][i] = ob;
                    #pragma unroll
                    for (int r = 0; r < NENT; ++r) {
                        float pp = ob * WrSh[r * D + i];
                        #pragma unroll
                        for (int off = 32; off; off >>= 1)
                            pp += __shfl_xor(pp, off);
                        if (lane == 0) lpart[wv][r] = pp;
                    }
                    int sn = (s + 1 < SEQ) ? s + 1 : s;
                    bwc = BW[sn * D + i];              // prefetch next row
                }
                __syncthreads();                       // barrier 2
                float lv2 = -FLT_MAX;
                if (lane < NENT)
                    lv2 = lpart[0][lane] + lpart[1][lane] + lpart[2][lane] +
                          lpart[3][lane] + brSh[lane];
                int am2; float pm2;
                grp_smax<8>(lv2, NENT, lane, am2, pm2);
                if (tid == 0) {
                    out[2 * SEQ + t * SEQ + s] = (float)am2;
                    out[2 * SEQ + SEQ * SEQ + t * SEQ + s] = pm2;
                }
                ab = am2;        // wave-uniform register, no LDS roundtrip
                p ^= 1;
            }
            // mem = Wbt @ membf + bbt
            float es = mv_half(WBTh, xbuf[p] + h * 128);
            if (!lower) pbuf[i] = es;
            __syncthreads();
            if (lower) mem[i] = es + pbuf[i] + bbt[i];
            __syncthreads();
        } else {
            if (lower) mem[i] = outv[i];
            if (tid < SEQ) {
                out[2 * SEQ + t * SEQ + tid] = 0.f;
                out[2 * SEQ + SEQ * SEQ + t * SEQ + tid] = 0.f;
            }
            __syncthreads();
        }
    }
}

// ---------------------------------------------------------------------------
extern "C" void kernel_launch(void* const* d_in, const int* in_sizes, int n_in,
                              void* d_out, int out_size, void* d_ws, size_t ws_size,
                              hipStream_t stream)
{
    (void)in_sizes; (void)n_in; (void)out_size; (void)ws_size;
    const int*   text       = (const int*)  d_in[0];
    const float* wordvector = (const float*)d_in[1];
    const float* relvec     = (const float*)d_in[2];
    const float* entvec     = (const float*)d_in[3];
    const float* WihL = (const float*)d_in[4];  const float* WhhL = (const float*)d_in[5];
    const float* bihL = (const float*)d_in[6];  const float* bhhL = (const float*)d_in[7];
    const float* WihR = (const float*)d_in[8];  const float* WhhR = (const float*)d_in[9];
    const float* bihR = (const float*)d_in[10]; const float* bhhR = (const float*)d_in[11];
    const float* Wt   = (const float*)d_in[12]; const float* bt   = (const float*)d_in[13];
    const float* Wp   = (const float*)d_in[14]; const float* bp   = (const float*)d_in[15];
    const float* Wb   = (const float*)d_in[16]; const float* bb   = (const float*)d_in[17];
    const float* Wpl  = (const float*)d_in[18]; const float* bpl  = (const float*)d_in[19];
    const float* Wtt  = (const float*)d_in[20]; const float* btt  = (const float*)d_in[21];
    const float* Wtb  = (const float*)d_in[22]; const float* btb  = (const float*)d_in[23];
    const float* Wbt  = (const float*)d_in[24]; const float* bbt  = (const float*)d_in[25];

    float* ws = (float*)d_ws;
    size_t o = 0;
    auto take = [&](size_t n) { float* p = ws + o; o += n; return p; };
    float* XGF    = take(SEQ * G);
    float* XGB    = take(SEQ * G);
    float* WHLT   = take(D * G);
    float* WHRT   = take(D * G);
    float* WORDIN = take(SEQ * 2 * D);
    float* TW     = take(SEQ * D);
    float* BW     = take(SEQ * D);
    float* RVb    = take(NREL * D);
    float* EVb    = take(NENT * D);
    float* WTWT   = take(2 * D * D);
    float* WTRT   = take(D * D);
    float* WTMT   = take(D * D);
    float* WBWT   = take(2 * D * D);
    float* WBET   = take(D * D);
    float* WBGT   = take(D * D);
    float* WTBT   = take(D * D);
    float* WBTT   = take(D * D);
    float* M1T    = take(D * D);
    float* C1     = take(D);
    float* WB2    = take(2 * 128 * D);   // 512 threads * 128 floats

    auto tr = [&](const float* in, float* outp, int rows, int cols, int stride, int off) {
        int n = rows * cols;
        k_trans<<<(n + 255) / 256, 256, 0, stream>>>(in, outp, rows, cols, stride, off);
    };
    tr(WhhL, WHLT, G, D, D, 0);          // WHLT[k*G + j] = WhhL[j][k]
    tr(WhhR, WHRT, G, D, D, 0);
    tr(Wt,  WTWT, D, 2 * D, G, 0);       // word part of Wt
    tr(Wt,  WTRT, D, D, G, 512);         // relvec part
    tr(Wt,  WTMT, D, D, G, 768);         // mem part
    tr(Wb,  WBWT, D, 2 * D, 5 * D, 0);   // word part of Wb
    tr(Wb,  WBET, D, D, 5 * D, 512);     // entvec part
    tr(Wb,  WBGT, D, D, 5 * D, 1024);    // target part (feeds M1/c1)
    tr(Wtb, WTBT, D, D, D, 0);
    tr(Wbt, WBTT, D, D, D, 0);

    k_m1<<<D, D, 0, stream>>>(WBGT, Wtt, M1T);
    k_c1<<<1, D, 0, stream>>>(WBGT, btt, C1);
    k_pack<<<256, 256, 0, stream>>>(Wb, WB2);

    k_xg<<<SEQ, 1024, 0, stream>>>(text, wordvector, WihL, bihL, bhhL, XGF);
    k_xg<<<SEQ, 1024, 0, stream>>>(text, wordvector, WihR, bihR, bhhR, XGB);
    k_lstm<<<2, 1024, 0, stream>>>(XGF, XGB, WHLT, WHRT, WORDIN);
    k_prep2<<<SEQ + NREL + NENT, 256, 0, stream>>>(WORDIN, WTWT, WBWT, WTRT, WBET,
                                                   relvec, entvec, bt, bb,
                                                   TW, BW, RVb, EVb);
    k_main2<<<1, 512, 0, stream>>>(TW, BW, RVb, EVb, WTMT, WTBT, WBTT, M1T, C1,
                                   WB2, Wp, bp, Wpl, bpl, btb, bbt,
                                   (float*)d_out);
}

// Round 4
// 60490.308 us; speedup vs baseline: 1.2646x; 1.0048x over previous
//
#include <hip/hip_runtime.h>
#include <float.h>

constexpr int SEQ  = 128;   // sentence length T
constexpr int D    = 256;   // DIM / STATEDIM
constexpr int G    = 1024;  // 4*DIM gate width
constexpr int NREL = 26;    // REL_COUNT + 1
constexpr int NENT = 7;

typedef float v2f __attribute__((ext_vector_type(2)));

// ---------------------------------------------------------------------------
// Generic strided transpose: out[k*rows + i] = in[i*in_stride + in_off + k]
// ---------------------------------------------------------------------------
__global__ void k_trans(const float* __restrict__ in, float* __restrict__ out,
                        int rows, int cols, int in_stride, int in_off)
{
    int idx = blockIdx.x * 256 + threadIdx.x;
    if (idx >= rows * cols) return;
    int i = idx % rows;
    int k = idx / rows;
    out[idx] = in[(size_t)i * in_stride + in_off + k];
}

// ---------------------------------------------------------------------------
// xg[t][j] = bih[j] + bhh[j] + sum_k wordvector[text[t]][k] * Wih[j][k]
// ---------------------------------------------------------------------------
__global__ __launch_bounds__(1024) void k_xg(
    const int* __restrict__ text, const float* __restrict__ wv,
    const float* __restrict__ Wih, const float* __restrict__ bih,
    const float* __restrict__ bhh, float* __restrict__ xg)
{
    int t = blockIdx.x, j = threadIdx.x;
    const float* x  = wv + (size_t)text[t] * D;
    const float* wr = Wih + (size_t)j * D;
    float acc = bih[j] + bhh[j];
    for (int k = 0; k < D; ++k) acc += x[k] * wr[k];
    xg[t * G + j] = acc;
}

// ---------------------------------------------------------------------------
// Sequential LSTM, one block per direction (grid=2), 1024 threads.
// ---------------------------------------------------------------------------
__global__ __launch_bounds__(1024) void k_lstm(
    const float* __restrict__ xgF, const float* __restrict__ xgB,
    const float* __restrict__ WHTF, const float* __restrict__ WHTB,
    float* __restrict__ wordin)
{
    int dir = blockIdx.x;
    const float* xg  = dir ? xgB  : xgF;
    const float* WHT = dir ? WHTB : WHTF;
    __shared__ float h[D], c[D], g[G];
    int j = threadIdx.x;
    if (j < D) { h[j] = 0.f; c[j] = 0.f; }
    __syncthreads();
    for (int s = 0; s < SEQ; ++s) {
        int t = dir ? (SEQ - 1 - s) : s;
        float acc = xg[t * G + j];
        for (int k = 0; k < D; ++k) acc += WHT[k * G + j] * h[k];
        g[j] = acc;
        __syncthreads();
        if (j < D) {
            float si = 1.f / (1.f + expf(-g[j]));
            float sf = 1.f / (1.f + expf(-g[D + j]));
            float gg = tanhf(g[2 * D + j]);
            float so = 1.f / (1.f + expf(-g[3 * D + j]));
            float cn = sf * c[j] + si * gg;
            float hn = so * tanhf(cn);
            c[j] = cn; h[j] = hn;
            wordin[t * (2 * D) + dir * D + j] = hn;
        }
        __syncthreads();
    }
}

// ---------------------------------------------------------------------------
// Parallel precompute after LSTM (TW/BW per word, RV per relation, EV per ent)
// ---------------------------------------------------------------------------
__global__ __launch_bounds__(256) void k_prep2(
    const float* __restrict__ wordin,
    const float* __restrict__ WTWT, const float* __restrict__ WBWT,
    const float* __restrict__ WTRT, const float* __restrict__ WBET,
    const float* __restrict__ relvec, const float* __restrict__ entvec,
    const float* __restrict__ btv, const float* __restrict__ bbv,
    float* __restrict__ TW, float* __restrict__ BW,
    float* __restrict__ RV, float* __restrict__ EV)
{
    int b = blockIdx.x, i = threadIdx.x;
    if (b < SEQ) {
        const float* w = wordin + b * (2 * D);
        float a1 = btv[i], a2 = bbv[i];
        for (int j = 0; j < 2 * D; ++j) {
            float wv = w[j];
            a1 += wv * WTWT[j * D + i];
            a2 += wv * WBWT[j * D + i];
        }
        TW[b * D + i] = a1;
        BW[b * D + i] = a2;
    } else if (b < SEQ + NREL) {
        int r = b - SEQ;
        const float* x = relvec + r * D;
        float a = 0.f;
        for (int k = 0; k < D; ++k) a += x[k] * WTRT[k * D + i];
        RV[r * D + i] = a;
    } else {
        int e = b - SEQ - NREL;
        const float* x = entvec + e * D;
        float a = 0.f;
        for (int k = 0; k < D; ++k) a += x[k] * WBET[k * D + i];
        EV[e * D + i] = a;
    }
}

// ---------------------------------------------------------------------------
// M1T[j*D + i] = sum_k WBGT[k*D+i] * Wtt[k*D+j]   (M1 = Wb_target @ Wtt)
// ---------------------------------------------------------------------------
__global__ __launch_bounds__(256) void k_m1(
    const float* __restrict__ WBGT, const float* __restrict__ Wtt,
    float* __restrict__ M1T)
{
    int j = blockIdx.x, i = threadIdx.x;
    float a = 0.f;
    for (int k = 0; k < D; ++k) a = fmaf(WBGT[k * D + i], Wtt[k * D + j], a);
    M1T[j * D + i] = a;
}

// c1[i] = sum_k WBGT[k*D+i] * btt[k]
__global__ __launch_bounds__(256) void k_c1(
    const float* __restrict__ WBGT, const float* __restrict__ btt,
    float* __restrict__ c1)
{
    int i = threadIdx.x;
    float a = 0.f;
    for (int k = 0; k < D; ++k) a = fmaf(WBGT[k * D + i], btt[k], a);
    c1[i] = a;
}

// ---------------------------------------------------------------------------
// Per-thread-contiguous pack of Wb_m for the register-resident bot matvec:
// WB2[tid*128 + kk] = Wb[i][768 + h*128 + kk],  tid = h*256+i
// ---------------------------------------------------------------------------
__global__ __launch_bounds__(256) void k_pack(
    const float* __restrict__ Wb, float* __restrict__ WB2)
{
    int e = blockIdx.x * 256 + threadIdx.x;      // 0..65535
    int tid = e >> 7, kk = e & 127;
    int h = tid >> 8, i = tid & 255;
    WB2[e] = Wb[(size_t)i * (5 * D) + 3 * D + h * 128 + kk];
}

// ---------------------------------------------------------------------------
// Streamed split-k half-matvec: Wcol points at W^T[k0*D + i] (k-major),
// x points at the LDS vector slice for this k-half. 4 independent chains.
// ---------------------------------------------------------------------------
__device__ inline float mv_half(const float* __restrict__ Wcol,
                                const float* __restrict__ x)
{
    float a0 = 0.f, a1 = 0.f, a2 = 0.f, a3 = 0.f;
    #pragma unroll
    for (int kk = 0; kk < 128; kk += 4) {
        a0 = fmaf(Wcol[(kk + 0) * D], x[kk + 0], a0);
        a1 = fmaf(Wcol[(kk + 1) * D], x[kk + 1], a1);
        a2 = fmaf(Wcol[(kk + 2) * D], x[kk + 2], a2);
        a3 = fmaf(Wcol[(kk + 3) * D], x[kk + 3], a3);
    }
    return (a0 + a1) + (a2 + a3);
}

// ---------------------------------------------------------------------------
// Softmax + first-occurrence argmax over n values living in lanes 0..n-1 of
// each W-lane group. Mimics reference: p = exp(l-max)/sum, argmax over p.
// Lanes >= n pass lv = -FLT_MAX. Result (am) is wave-uniform (ballot-based);
// spurious ballot bits from other groups are all >= W so ffsll stays correct.
// ---------------------------------------------------------------------------
template<int W>
__device__ inline void grp_smax(float lv, int n, int lane, int& am, float& pm)
{
    float mx = lv;
    #pragma unroll
    for (int off = W / 2; off; off >>= 1) mx = fmaxf(mx, __shfl_xor(mx, off));
    float e  = (lane < n) ? expf(lv - mx) : 0.f;
    float se = e;
    #pragma unroll
    for (int off = W / 2; off; off >>= 1) se += __shfl_xor(se, off);
    float p  = (lane < n) ? (e / se) : -1.f;
    float q  = p;
    #pragma unroll
    for (int off = W / 2; off; off >>= 1) q = fmaxf(q, __shfl_xor(q, off));
    unsigned long long mask = __ballot(p == q);
    am = __ffsll((long long)mask) - 1;
    pm = q;
}

// ---------------------------------------------------------------------------
// Sequential main kernel: 1 block, 512 threads = 8 waves = 2 waves/SIMD.
// amdgpu_waves_per_eu(2,2) pins the allocator target at 2 waves/EU so the
// 128-reg weight block may occupy up to 256 VGPRs. The asm round-trip after
// the weight load makes the values un-rematerializable (R2/R3 failure: the
// allocator targeted 4 waves/EU and re-issued the weight loads every step,
// 4.3 GB of scratch-class traffic).
// ---------------------------------------------------------------------------
__global__ __launch_bounds__(512)
__attribute__((amdgpu_waves_per_eu(2, 2)))
void k_main2(
    const float* __restrict__ TW,   const float* __restrict__ BW,
    const float* __restrict__ RV,   const float* __restrict__ EV,
    const float* __restrict__ WTMT, const float* __restrict__ WTBT,
    const float* __restrict__ WBTT, const float* __restrict__ M1T,
    const float* __restrict__ c1v,  const float* __restrict__ WB2,
    const float* __restrict__ Wp,   const float* __restrict__ bp,
    const float* __restrict__ Wpl,  const float* __restrict__ bpl,
    const float* __restrict__ btb,  const float* __restrict__ bbt,
    float* __restrict__ out)
{
    const int tid  = threadIdx.x;
    const int lane = tid & 63;
    const int wv   = tid >> 6;        // wave id 0..7
    const int h    = tid >> 8;        // k-half
    const int i    = tid & 255;       // output index
    const bool lower = (tid < 256);

    __shared__ __align__(16) float xbuf[2][D];
    __shared__ __align__(16) float pbuf[D], pbufB[D], pbufC[D];
    __shared__ __align__(16) float mem[D], outv[D];
    __shared__ __align__(16) float WrSh[NENT * D];
    __shared__ float lpart[4][32];
    __shared__ float brSh[8];

    // register-resident W_bm half-column (per-thread contiguous pack)
    v2f w2[64];
    {
        const v2f* src = reinterpret_cast<const v2f*>(WB2) + tid * 64;
        #pragma unroll
        for (int q = 0; q < 64; ++q) w2[q] = src[q];
    }
    // pin: forbid rematerialization of the weight loads
    #pragma unroll
    for (int q = 0; q < 64; ++q) {
        double dp = __builtin_bit_cast(double, w2[q]);
        asm volatile("" : "+v"(dp));
        w2[q] = __builtin_bit_cast(v2f, dp);
    }
    // loop-invariant entity columns, register-resident (lower half only)
    float ev0 = 0.f, ev1 = 0.f, ev2 = 0.f, ev3 = 0.f,
          ev4 = 0.f, ev5 = 0.f, ev6 = 0.f;
    if (lower) {
        ev0 = EV[0 * D + i]; ev1 = EV[1 * D + i]; ev2 = EV[2 * D + i];
        ev3 = EV[3 * D + i]; ev4 = EV[4 * D + i]; ev5 = EV[5 * D + i];
        ev6 = EV[6 * D + i];
        mem[i] = 0.f;
    }
    __syncthreads();

    const float* WTMh = WTMT + (size_t)h * 128 * D + i;
    const float* WTBh = WTBT + (size_t)h * 128 * D + i;
    const float* WBTh = WBTT + (size_t)h * 128 * D + i;
    const float* M1h  = M1T  + (size_t)h * 128 * D + i;

    int rel = 0;

    for (int t = 0; t < SEQ; ++t) {
        // ---- top step: outp = tanh(TW[t] + RV[rel] + Wt_m @ mem) ----
        float a = mv_half(WTMh, mem + h * 128);
        if (!lower) pbuf[i] = a;
        __syncthreads();
        if (lower) {
            float tot  = a + pbuf[i] + TW[t * D + i] + RV[rel * D + i];
            float outp = tanhf(tot);
            outv[i] = outp;
            #pragma unroll
            for (int r = 0; r < NREL; ++r) {
                float pp = outp * Wp[r * D + i];
                #pragma unroll
                for (int off = 32; off; off >>= 1) pp += __shfl_xor(pp, off);
                if (lane == 0) lpart[wv][r] = pp;
            }
        }
        __syncthreads();
        float lv = -FLT_MAX;
        if (lane < NREL)
            lv = lpart[0][lane] + lpart[1][lane] + lpart[2][lane] +
                 lpart[3][lane] + bp[lane];
        int am; float pm;
        grp_smax<32>(lv, NREL, lane, am, pm);
        if (tid == 0) { out[t] = (float)am; out[SEQ + t] = pm; }
        const int action = am;   // wave-uniform

        if (action > 0) {
            rel = action;
            // memb0 = Wtb@outp + btb ;  btm = M1@outp + c1  (tgt folded away)
            float bs = mv_half(WTBh, outv + h * 128);
            float cs = mv_half(M1h,  outv + h * 128);
            if (!lower) { pbufB[i] = bs; pbufC[i] = cs; }
            const size_t wbase = (size_t)(action - 1) * NENT * D;
            for (int k = tid; k < NENT * D; k += 512) WrSh[k] = Wpl[wbase + k];
            if (tid < NENT) brSh[tid] = bpl[(action - 1) * NENT + tid];
            __syncthreads();
            float btm = 0.f, bwc = 0.f;
            if (lower) {
                xbuf[0][i] = bs + pbufB[i] + btb[i];
                btm = cs + pbufC[i] + c1v[i];
                bwc = BW[i];          // prefetch BW row 0
            }
            __syncthreads();

            int p = 0, ab = 0;
            for (int s = 0; s < SEQ; ++s) {
                // -- matvec W_bm @ x: packed f32 FMA from registers --
                const float4* xb =
                    reinterpret_cast<const float4*>(xbuf[p] + h * 128);
                v2f A0 = {0.f, 0.f}, A1 = {0.f, 0.f},
                    A2 = {0.f, 0.f}, A3 = {0.f, 0.f};
                #pragma unroll
                for (int q = 0; q < 32; q += 2) {
                    float4 x0 = xb[q], x1 = xb[q + 1];
                    v2f xa = {x0.x, x0.y}, xc = {x0.z, x0.w};
                    v2f xd = {x1.x, x1.y}, xe = {x1.z, x1.w};
                    A0 = __builtin_elementwise_fma(w2[2 * q + 0], xa, A0);
                    A1 = __builtin_elementwise_fma(w2[2 * q + 1], xc, A1);
                    A2 = __builtin_elementwise_fma(w2[2 * q + 2], xd, A2);
                    A3 = __builtin_elementwise_fma(w2[2 * q + 3], xe, A3);
                }
                float ms = ((A0.x + A0.y) + (A1.x + A1.y)) +
                           ((A2.x + A2.y) + (A3.x + A3.y));
                if (!lower) pbuf[i] = ms;
                __syncthreads();                       // barrier 1
                if (lower) {
                    float ev = (ab == 0) ? ev0 : (ab == 1) ? ev1 :
                               (ab == 2) ? ev2 : (ab == 3) ? ev3 :
                               (ab == 4) ? ev4 : (ab == 5) ? ev5 : ev6;
                    float tot = ms + pbuf[i] + bwc + ev + btm;
                    float ob = tanhf(tot);
                    xbuf[p ^ 1][i] = ob;
                    #pragma unroll
                    for (int r = 0; r < NENT; ++r) {
                        float pp = ob * WrSh[r * D + i];
                        #pragma unroll
                        for (int off = 32; off; off >>= 1)
                            pp += __shfl_xor(pp, off);
                        if (lane == 0) lpart[wv][r] = pp;
                    }
                    int sn = (s + 1 < SEQ) ? s + 1 : s;
                    bwc = BW[sn * D + i];              // prefetch next row
                }
                __syncthreads();                       // barrier 2
                float lv2 = -FLT_MAX;
                if (lane < NENT)
                    lv2 = lpart[0][lane] + lpart[1][lane] + lpart[2][lane] +
                          lpart[3][lane] + brSh[lane];
                int am2; float pm2;
                grp_smax<8>(lv2, NENT, lane, am2, pm2);
                if (tid == 0) {
                    out[2 * SEQ + t * SEQ + s] = (float)am2;
                    out[2 * SEQ + SEQ * SEQ + t * SEQ + s] = pm2;
                }
                ab = am2;        // wave-uniform register, no LDS roundtrip
                p ^= 1;
            }
            // mem = Wbt @ membf + bbt
            float es = mv_half(WBTh, xbuf[p] + h * 128);
            if (!lower) pbuf[i] = es;
            __syncthreads();
            if (lower) mem[i] = es + pbuf[i] + bbt[i];
            __syncthreads();
        } else {
            if (lower) mem[i] = outv[i];
            if (tid < SEQ) {
                out[2 * SEQ + t * SEQ + tid] = 0.f;
                out[2 * SEQ + SEQ * SEQ + t * SEQ + tid] = 0.f;
            }
            __syncthreads();
        }
    }
}

// ---------------------------------------------------------------------------
extern "C" void kernel_launch(void* const* d_in, const int* in_sizes, int n_in,
                              void* d_out, int out_size, void* d_ws, size_t ws_size,
                              hipStream_t stream)
{
    (void)in_sizes; (void)n_in; (void)out_size; (void)ws_size;
    const int*   text       = (const int*)  d_in[0];
    const float* wordvector = (const float*)d_in[1];
    const float* relvec     = (const float*)d_in[2];
    const float* entvec     = (const float*)d_in[3];
    const float* WihL = (const float*)d_in[4];  const float* WhhL = (const float*)d_in[5];
    const float* bihL = (const float*)d_in[6];  const float* bhhL = (const float*)d_in[7];
    const float* WihR = (const float*)d_in[8];  const float* WhhR = (const float*)d_in[9];
    const float* bihR = (const float*)d_in[10]; const float* bhhR = (const float*)d_in[11];
    const float* Wt   = (const float*)d_in[12]; const float* bt   = (const float*)d_in[13];
    const float* Wp   = (const float*)d_in[14]; const float* bp   = (const float*)d_in[15];
    const float* Wb   = (const float*)d_in[16]; const float* bb   = (const float*)d_in[17];
    const float* Wpl  = (const float*)d_in[18]; const float* bpl  = (const float*)d_in[19];
    const float* Wtt  = (const float*)d_in[20]; const float* btt  = (const float*)d_in[21];
    const float* Wtb  = (const float*)d_in[22]; const float* btb  = (const float*)d_in[23];
    const float* Wbt  = (const float*)d_in[24]; const float* bbt  = (const float*)d_in[25];

    float* ws = (float*)d_ws;
    size_t o = 0;
    auto take = [&](size_t n) { float* p = ws + o; o += n; return p; };
    float* XGF    = take(SEQ * G);
    float* XGB    = take(SEQ * G);
    float* WHLT   = take(D * G);
    float* WHRT   = take(D * G);
    float* WORDIN = take(SEQ * 2 * D);
    float* TW     = take(SEQ * D);
    float* BW     = take(SEQ * D);
    float* RVb    = take(NREL * D);
    float* EVb    = take(NENT * D);
    float* WTWT   = take(2 * D * D);
    float* WTRT   = take(D * D);
    float* WTMT   = take(D * D);
    float* WBWT   = take(2 * D * D);
    float* WBET   = take(D * D);
    float* WBGT   = take(D * D);
    float* WTBT   = take(D * D);
    float* WBTT   = take(D * D);
    float* M1T    = take(D * D);
    float* C1     = take(D);
    float* WB2    = take(2 * 128 * D);   // 512 threads * 128 floats

    auto tr = [&](const float* in, float* outp, int rows, int cols, int stride, int off) {
        int n = rows * cols;
        k_trans<<<(n + 255) / 256, 256, 0, stream>>>(in, outp, rows, cols, stride, off);
    };
    tr(WhhL, WHLT, G, D, D, 0);          // WHLT[k*G + j] = WhhL[j][k]
    tr(WhhR, WHRT, G, D, D, 0);
    tr(Wt,  WTWT, D, 2 * D, G, 0);       // word part of Wt
    tr(Wt,  WTRT, D, D, G, 512);         // relvec part
    tr(Wt,  WTMT, D, D, G, 768);         // mem part
    tr(Wb,  WBWT, D, 2 * D, 5 * D, 0);   // word part of Wb
    tr(Wb,  WBET, D, D, 5 * D, 512);     // entvec part
    tr(Wb,  WBGT, D, D, 5 * D, 1024);    // target part (feeds M1/c1)
    tr(Wtb, WTBT, D, D, D, 0);
    tr(Wbt, WBTT, D, D, D, 0);

    k_m1<<<D, D, 0, stream>>>(WBGT, Wtt, M1T);
    k_c1<<<1, D, 0, stream>>>(WBGT, btt, C1);
    k_pack<<<256, 256, 0, stream>>>(Wb, WB2);

    k_xg<<<SEQ, 1024, 0, stream>>>(text, wordvector, WihL, bihL, bhhL, XGF);
    k_xg<<<SEQ, 1024, 0, stream>>>(text, wordvector, WihR, bihR, bhhR, XGB);
    k_lstm<<<2, 1024, 0, stream>>>(XGF, XGB, WHLT, WHRT, WORDIN);
    k_prep2<<<SEQ + NREL + NENT, 256, 0, stream>>>(WORDIN, WTWT, WBWT, WTRT, WBET,
                                                   relvec, entvec, bt, bb,
                                                   TW, BW, RVb, EVb);
    k_main2<<<1, 512, 0, stream>>>(TW, BW, RVb, EVb, WTMT, WTBT, WBTT, M1T, C1,
                                   WB2, Wp, bp, Wpl, bpl, btb, bbt,
                                   (float*)d_out);
}

// Round 5
// 57848.511 us; speedup vs baseline: 1.3224x; 1.0457x over previous
//
#include <hip/hip_runtime.h>
#include <float.h>

constexpr int SEQ  = 128;   // sentence length T
constexpr int D    = 256;   // DIM / STATEDIM
constexpr int G    = 1024;  // 4*DIM gate width
constexpr int NREL = 26;    // REL_COUNT + 1
constexpr int NENT = 7;

typedef float v2f __attribute__((ext_vector_type(2)));

// ---------------------------------------------------------------------------
// Generic strided transpose: out[k*rows + i] = in[i*in_stride + in_off + k]
// ---------------------------------------------------------------------------
__global__ void k_trans(const float* __restrict__ in, float* __restrict__ out,
                        int rows, int cols, int in_stride, int in_off)
{
    int idx = blockIdx.x * 256 + threadIdx.x;
    if (idx >= rows * cols) return;
    int i = idx % rows;
    int k = idx / rows;
    out[idx] = in[(size_t)i * in_stride + in_off + k];
}

// ---------------------------------------------------------------------------
// xg[t][j] = bih[j] + bhh[j] + sum_k wordvector[text[t]][k] * Wih[j][k]
// ---------------------------------------------------------------------------
__global__ __launch_bounds__(1024) void k_xg(
    const int* __restrict__ text, const float* __restrict__ wv,
    const float* __restrict__ Wih, const float* __restrict__ bih,
    const float* __restrict__ bhh, float* __restrict__ xg)
{
    int t = blockIdx.x, j = threadIdx.x;
    const float* x  = wv + (size_t)text[t] * D;
    const float* wr = Wih + (size_t)j * D;
    float acc = bih[j] + bhh[j];
    for (int k = 0; k < D; ++k) acc += x[k] * wr[k];
    xg[t * G + j] = acc;
}

// ---------------------------------------------------------------------------
// Sequential LSTM, one block per direction (grid=2), 1024 threads.
// ---------------------------------------------------------------------------
__global__ __launch_bounds__(1024) void k_lstm(
    const float* __restrict__ xgF, const float* __restrict__ xgB,
    const float* __restrict__ WHTF, const float* __restrict__ WHTB,
    float* __restrict__ wordin)
{
    int dir = blockIdx.x;
    const float* xg  = dir ? xgB  : xgF;
    const float* WHT = dir ? WHTB : WHTF;
    __shared__ float h[D], c[D], g[G];
    int j = threadIdx.x;
    if (j < D) { h[j] = 0.f; c[j] = 0.f; }
    __syncthreads();
    for (int s = 0; s < SEQ; ++s) {
        int t = dir ? (SEQ - 1 - s) : s;
        float acc = xg[t * G + j];
        for (int k = 0; k < D; ++k) acc += WHT[k * G + j] * h[k];
        g[j] = acc;
        __syncthreads();
        if (j < D) {
            float si = 1.f / (1.f + expf(-g[j]));
            float sf = 1.f / (1.f + expf(-g[D + j]));
            float gg = tanhf(g[2 * D + j]);
            float so = 1.f / (1.f + expf(-g[3 * D + j]));
            float cn = sf * c[j] + si * gg;
            float hn = so * tanhf(cn);
            c[j] = cn; h[j] = hn;
            wordin[t * (2 * D) + dir * D + j] = hn;
        }
        __syncthreads();
    }
}

// ---------------------------------------------------------------------------
// Parallel precompute after LSTM (TW/BW per word, RV per relation, EV per ent)
// ---------------------------------------------------------------------------
__global__ __launch_bounds__(256) void k_prep2(
    const float* __restrict__ wordin,
    const float* __restrict__ WTWT, const float* __restrict__ WBWT,
    const float* __restrict__ WTRT, const float* __restrict__ WBET,
    const float* __restrict__ relvec, const float* __restrict__ entvec,
    const float* __restrict__ btv, const float* __restrict__ bbv,
    float* __restrict__ TW, float* __restrict__ BW,
    float* __restrict__ RV, float* __restrict__ EV)
{
    int b = blockIdx.x, i = threadIdx.x;
    if (b < SEQ) {
        const float* w = wordin + b * (2 * D);
        float a1 = btv[i], a2 = bbv[i];
        for (int j = 0; j < 2 * D; ++j) {
            float wv = w[j];
            a1 += wv * WTWT[j * D + i];
            a2 += wv * WBWT[j * D + i];
        }
        TW[b * D + i] = a1;
        BW[b * D + i] = a2;
    } else if (b < SEQ + NREL) {
        int r = b - SEQ;
        const float* x = relvec + r * D;
        float a = 0.f;
        for (int k = 0; k < D; ++k) a += x[k] * WTRT[k * D + i];
        RV[r * D + i] = a;
    } else {
        int e = b - SEQ - NREL;
        const float* x = entvec + e * D;
        float a = 0.f;
        for (int k = 0; k < D; ++k) a += x[k] * WBET[k * D + i];
        EV[e * D + i] = a;
    }
}

// ---------------------------------------------------------------------------
// M1T[j*D + i] = sum_k WBGT[k*D+i] * Wtt[k*D+j]   (M1 = Wb_target @ Wtt)
// ---------------------------------------------------------------------------
__global__ __launch_bounds__(256) void k_m1(
    const float* __restrict__ WBGT, const float* __restrict__ Wtt,
    float* __restrict__ M1T)
{
    int j = blockIdx.x, i = threadIdx.x;
    float a = 0.f;
    for (int k = 0; k < D; ++k) a = fmaf(WBGT[k * D + i], Wtt[k * D + j], a);
    M1T[j * D + i] = a;
}

// c1[i] = sum_k WBGT[k*D+i] * btt[k]
__global__ __launch_bounds__(256) void k_c1(
    const float* __restrict__ WBGT, const float* __restrict__ btt,
    float* __restrict__ c1)
{
    int i = threadIdx.x;
    float a = 0.f;
    for (int k = 0; k < D; ++k) a = fmaf(WBGT[k * D + i], btt[k], a);
    c1[i] = a;
}

// ---------------------------------------------------------------------------
// Per-thread-contiguous pack of Wb_m for the 4-way split-k register matvec:
// WB4[tid*64 + kk] = Wb[i][768 + q*64 + kk],  tid = q*256+i  (1024 threads)
// ---------------------------------------------------------------------------
__global__ __launch_bounds__(256) void k_pack4(
    const float* __restrict__ Wb, float* __restrict__ WB4)
{
    int e = blockIdx.x * 256 + threadIdx.x;      // 0..65535
    int tid = e >> 6, kk = e & 63;
    int q = tid >> 8, i = tid & 255;
    WB4[e] = Wb[(size_t)i * (5 * D) + 3 * D + q * 64 + kk];
}

// ---------------------------------------------------------------------------
// Streamed split-k quarter matvec: Wcol points at W^T[k0*D + i] (k-major),
// x points at the LDS vector slice for this k-quarter. 4 independent chains.
// ---------------------------------------------------------------------------
__device__ inline float mv_q(const float* __restrict__ Wcol,
                             const float* __restrict__ x)
{
    float a0 = 0.f, a1 = 0.f, a2 = 0.f, a3 = 0.f;
    #pragma unroll
    for (int kk = 0; kk < 64; kk += 4) {
        a0 = fmaf(Wcol[(kk + 0) * D], x[kk + 0], a0);
        a1 = fmaf(Wcol[(kk + 1) * D], x[kk + 1], a1);
        a2 = fmaf(Wcol[(kk + 2) * D], x[kk + 2], a2);
        a3 = fmaf(Wcol[(kk + 3) * D], x[kk + 3], a3);
    }
    return (a0 + a1) + (a2 + a3);
}

// ---------------------------------------------------------------------------
// Softmax + first-occurrence argmax over n values living in lanes 0..n-1 of
// each W-lane group. Mimics reference: p = exp(l-max)/sum, argmax over p.
// Lanes >= n pass lv = -FLT_MAX; their p=-1 matches only bits >= n, so the
// ffsll result (lowest set bit) always comes from the real group. Wave-uniform.
// ---------------------------------------------------------------------------
template<int W>
__device__ inline void grp_smax(float lv, int n, int lane, int& am, float& pm)
{
    float mx = lv;
    #pragma unroll
    for (int off = W / 2; off; off >>= 1) mx = fmaxf(mx, __shfl_xor(mx, off));
    float e  = (lane < n) ? expf(lv - mx) : 0.f;
    float se = e;
    #pragma unroll
    for (int off = W / 2; off; off >>= 1) se += __shfl_xor(se, off);
    float p  = (lane < n) ? (e / se) : -1.f;
    float q  = p;
    #pragma unroll
    for (int off = W / 2; off; off >>= 1) q = fmaxf(q, __shfl_xor(q, off));
    unsigned long long mask = __ballot(p == q);
    am = __ffsll((long long)mask) - 1;
    pm = q;
}

// ---------------------------------------------------------------------------
// Sequential main kernel: 1 block, 1024 threads = 16 waves = 4 waves/SIMD.
// Designed to FIT the compiler's 128-VGPR budget (R2-R4 failure: 128-reg
// weight block at 2 waves/EU was spilled to scratch regardless of hints).
// Thread tid = q*256+i: output i, k-quarter q. 64 weight floats/thread
// (32 v2f = 64 VGPRs). Partials combined via LDS psA[4][256].
// ---------------------------------------------------------------------------
__global__ __launch_bounds__(1024, 4)
void k_main3(
    const float* __restrict__ TW,   const float* __restrict__ BW,
    const float* __restrict__ RV,   const float* __restrict__ EV,
    const float* __restrict__ WTMT, const float* __restrict__ WTBT,
    const float* __restrict__ WBTT, const float* __restrict__ M1T,
    const float* __restrict__ c1v,  const float* __restrict__ WB4,
    const float* __restrict__ Wp,   const float* __restrict__ bp,
    const float* __restrict__ Wpl,  const float* __restrict__ bpl,
    const float* __restrict__ btb,  const float* __restrict__ bbt,
    float* __restrict__ out)
{
    const int tid  = threadIdx.x;
    const int lane = tid & 63;
    const int lwv  = (tid >> 6) & 3;  // wave index within quarter
    const int q    = tid >> 8;        // k-quarter 0..3
    const int i    = tid & 255;       // output index
    const bool lower = (tid < 256);

    __shared__ __align__(16) float xbuf[2][D];
    __shared__ __align__(16) float psA[4][D], psB[4][D];
    __shared__ __align__(16) float mem[D], outv[D];
    __shared__ __align__(16) float WrSh[NENT * D];
    __shared__ float lpart[4][32];
    __shared__ float brSh[8];

    // register-resident W_bm quarter-column (per-thread contiguous pack)
    v2f w2[32];
    {
        const float4* src = reinterpret_cast<const float4*>(WB4) + tid * 16;
        #pragma unroll
        for (int k4 = 0; k4 < 16; ++k4) {
            float4 v = src[k4];
            w2[2 * k4 + 0] = (v2f){v.x, v.y};
            w2[2 * k4 + 1] = (v2f){v.z, v.w};
        }
    }
    // pin: forbid rematerialization of the weight loads
    #pragma unroll
    for (int k2 = 0; k2 < 32; ++k2) {
        double dp = __builtin_bit_cast(double, w2[k2]);
        asm volatile("" : "+v"(dp));
        w2[k2] = __builtin_bit_cast(v2f, dp);
    }
    // loop-invariant entity columns, register-resident (lower quarter only)
    float ev0 = 0.f, ev1 = 0.f, ev2 = 0.f, ev3 = 0.f,
          ev4 = 0.f, ev5 = 0.f, ev6 = 0.f;
    if (lower) {
        ev0 = EV[0 * D + i]; ev1 = EV[1 * D + i]; ev2 = EV[2 * D + i];
        ev3 = EV[3 * D + i]; ev4 = EV[4 * D + i]; ev5 = EV[5 * D + i];
        ev6 = EV[6 * D + i];
        mem[i] = 0.f;
    }
    __syncthreads();

    const float* WTMq = WTMT + (size_t)q * 64 * D + i;
    const float* WTBq = WTBT + (size_t)q * 64 * D + i;
    const float* WBTq = WBTT + (size_t)q * 64 * D + i;
    const float* M1q  = M1T  + (size_t)q * 64 * D + i;

    int rel = 0;

    for (int t = 0; t < SEQ; ++t) {
        // ---- top step: outp = tanh(TW[t] + RV[rel] + Wt_m @ mem) ----
        psA[q][i] = mv_q(WTMq, mem + q * 64);
        __syncthreads();
        if (lower) {
            float tot = psA[0][i] + psA[1][i] + psA[2][i] + psA[3][i] +
                        TW[t * D + i] + RV[rel * D + i];
            float outp = tanhf(tot);
            outv[i] = outp;
            #pragma unroll
            for (int r = 0; r < NREL; ++r) {
                float pp = outp * Wp[r * D + i];
                #pragma unroll
                for (int off = 32; off; off >>= 1) pp += __shfl_xor(pp, off);
                if (lane == 0) lpart[lwv][r] = pp;
            }
        }
        __syncthreads();
        float lv = -FLT_MAX;
        if (lane < NREL)
            lv = lpart[0][lane] + lpart[1][lane] + lpart[2][lane] +
                 lpart[3][lane] + bp[lane];
        int am; float pm;
        grp_smax<32>(lv, NREL, lane, am, pm);
        if (tid == 0) { out[t] = (float)am; out[SEQ + t] = pm; }
        const int action = am;   // wave-uniform

        if (action > 0) {
            rel = action;
            // memb0 = Wtb@outp + btb ;  btm = M1@outp + c1  (tgt folded away)
            psA[q][i] = mv_q(WTBq, outv + q * 64);
            psB[q][i] = mv_q(M1q,  outv + q * 64);
            const size_t wbase = (size_t)(action - 1) * NENT * D;
            for (int k = tid; k < NENT * D; k += 1024) WrSh[k] = Wpl[wbase + k];
            if (tid < NENT) brSh[tid] = bpl[(action - 1) * NENT + tid];
            __syncthreads();
            float btm = 0.f, bwc = 0.f;
            if (lower) {
                xbuf[0][i] = psA[0][i] + psA[1][i] + psA[2][i] + psA[3][i] +
                             btb[i];
                btm = psB[0][i] + psB[1][i] + psB[2][i] + psB[3][i] + c1v[i];
                bwc = BW[i];          // prefetch BW row 0
            }
            __syncthreads();

            int p = 0, ab = 0;
            for (int s = 0; s < SEQ; ++s) {
                // -- matvec quarter: packed f32 FMA from registers --
                const float4* xb =
                    reinterpret_cast<const float4*>(xbuf[p] + q * 64);
                v2f A0 = {0.f, 0.f}, A1 = {0.f, 0.f},
                    A2 = {0.f, 0.f}, A3 = {0.f, 0.f};
                #pragma unroll
                for (int k4 = 0; k4 < 16; k4 += 4) {
                    float4 x0 = xb[k4], x1 = xb[k4 + 1],
                           x2 = xb[k4 + 2], x3 = xb[k4 + 3];
                    A0 = __builtin_elementwise_fma(w2[2 * k4 + 0], (v2f){x0.x, x0.y}, A0);
                    A0 = __builtin_elementwise_fma(w2[2 * k4 + 1], (v2f){x0.z, x0.w}, A0);
                    A1 = __builtin_elementwise_fma(w2[2 * k4 + 2], (v2f){x1.x, x1.y}, A1);
                    A1 = __builtin_elementwise_fma(w2[2 * k4 + 3], (v2f){x1.z, x1.w}, A1);
                    A2 = __builtin_elementwise_fma(w2[2 * k4 + 4], (v2f){x2.x, x2.y}, A2);
                    A2 = __builtin_elementwise_fma(w2[2 * k4 + 5], (v2f){x2.z, x2.w}, A2);
                    A3 = __builtin_elementwise_fma(w2[2 * k4 + 6], (v2f){x3.x, x3.y}, A3);
                    A3 = __builtin_elementwise_fma(w2[2 * k4 + 7], (v2f){x3.z, x3.w}, A3);
                }
                v2f AS = (A0 + A1) + (A2 + A3);
                float ms = AS.x + AS.y;
                psA[q][i] = ms;
                __syncthreads();                       // barrier 1
                if (lower) {
                    float ev = (ab == 0) ? ev0 : (ab == 1) ? ev1 :
                               (ab == 2) ? ev2 : (ab == 3) ? ev3 :
                               (ab == 4) ? ev4 : (ab == 5) ? ev5 : ev6;
                    float tot = ms + psA[1][i] + psA[2][i] + psA[3][i] +
                                bwc + ev + btm;
                    float ob = tanhf(tot);
                    xbuf[p ^ 1][i] = ob;
                    #pragma unroll
                    for (int r = 0; r < NENT; ++r) {
                        float pp = ob * WrSh[r * D + i];
                        #pragma unroll
                        for (int off = 32; off; off >>= 1)
                            pp += __shfl_xor(pp, off);
                        if (lane == 0) lpart[lwv][r] = pp;
                    }
                    int sn = (s + 1 < SEQ) ? s + 1 : s;
                    bwc = BW[sn * D + i];              // prefetch next row
                }
                __syncthreads();                       // barrier 2
                float lv2 = -FLT_MAX;
                if (lane < NENT)
                    lv2 = lpart[0][lane] + lpart[1][lane] + lpart[2][lane] +
                          lpart[3][lane] + brSh[lane];
                int am2; float pm2;
                grp_smax<8>(lv2, NENT, lane, am2, pm2);
                if (tid == 0) {
                    out[2 * SEQ + t * SEQ + s] = (float)am2;
                    out[2 * SEQ + SEQ * SEQ + t * SEQ + s] = pm2;
                }
                ab = am2;        // wave-uniform register, no LDS roundtrip
                p ^= 1;
            }
            // mem = Wbt @ membf + bbt
            psA[q][i] = mv_q(WBTq, xbuf[p] + q * 64);
            __syncthreads();
            if (lower)
                mem[i] = psA[0][i] + psA[1][i] + psA[2][i] + psA[3][i] +
                         bbt[i];
            __syncthreads();
        } else {
            if (lower) mem[i] = outv[i];
            if (tid < SEQ) {
                out[2 * SEQ + t * SEQ + tid] = 0.f;
                out[2 * SEQ + SEQ * SEQ + t * SEQ + tid] = 0.f;
            }
            __syncthreads();
        }
    }
}

// ---------------------------------------------------------------------------
extern "C" void kernel_launch(void* const* d_in, const int* in_sizes, int n_in,
                              void* d_out, int out_size, void* d_ws, size_t ws_size,
                              hipStream_t stream)
{
    (void)in_sizes; (void)n_in; (void)out_size; (void)ws_size;
    const int*   text       = (const int*)  d_in[0];
    const float* wordvector = (const float*)d_in[1];
    const float* relvec     = (const float*)d_in[2];
    const float* entvec     = (const float*)d_in[3];
    const float* WihL = (const float*)d_in[4];  const float* WhhL = (const float*)d_in[5];
    const float* bihL = (const float*)d_in[6];  const float* bhhL = (const float*)d_in[7];
    const float* WihR = (const float*)d_in[8];  const float* WhhR = (const float*)d_in[9];
    const float* bihR = (const float*)d_in[10]; const float* bhhR = (const float*)d_in[11];
    const float* Wt   = (const float*)d_in[12]; const float* bt   = (const float*)d_in[13];
    const float* Wp   = (const float*)d_in[14]; const float* bp   = (const float*)d_in[15];
    const float* Wb   = (const float*)d_in[16]; const float* bb   = (const float*)d_in[17];
    const float* Wpl  = (const float*)d_in[18]; const float* bpl  = (const float*)d_in[19];
    const float* Wtt  = (const float*)d_in[20]; const float* btt  = (const float*)d_in[21];
    const float* Wtb  = (const float*)d_in[22]; const float* btb  = (const float*)d_in[23];
    const float* Wbt  = (const float*)d_in[24]; const float* bbt  = (const float*)d_in[25];

    float* ws = (float*)d_ws;
    size_t o = 0;
    auto take = [&](size_t n) { float* p = ws + o; o += n; return p; };
    float* XGF    = take(SEQ * G);
    float* XGB    = take(SEQ * G);
    float* WHLT   = take(D * G);
    float* WHRT   = take(D * G);
    float* WORDIN = take(SEQ * 2 * D);
    float* TW     = take(SEQ * D);
    float* BW     = take(SEQ * D);
    float* RVb    = take(NREL * D);
    float* EVb    = take(NENT * D);
    float* WTWT   = take(2 * D * D);
    float* WTRT   = take(D * D);
    float* WTMT   = take(D * D);
    float* WBWT   = take(2 * D * D);
    float* WBET   = take(D * D);
    float* WBGT   = take(D * D);
    float* WTBT   = take(D * D);
    float* WBTT   = take(D * D);
    float* M1T    = take(D * D);
    float* C1     = take(D);
    float* WB4    = take(1024 * 64);     // 1024 threads * 64 floats

    auto tr = [&](const float* in, float* outp, int rows, int cols, int stride, int off) {
        int n = rows * cols;
        k_trans<<<(n + 255) / 256, 256, 0, stream>>>(in, outp, rows, cols, stride, off);
    };
    tr(WhhL, WHLT, G, D, D, 0);          // WHLT[k*G + j] = WhhL[j][k]
    tr(WhhR, WHRT, G, D, D, 0);
    tr(Wt,  WTWT, D, 2 * D, G, 0);       // word part of Wt
    tr(Wt,  WTRT, D, D, G, 512);         // relvec part
    tr(Wt,  WTMT, D, D, G, 768);         // mem part
    tr(Wb,  WBWT, D, 2 * D, 5 * D, 0);   // word part of Wb
    tr(Wb,  WBET, D, D, 5 * D, 512);     // entvec part
    tr(Wb,  WBGT, D, D, 5 * D, 1024);    // target part (feeds M1/c1)
    tr(Wtb, WTBT, D, D, D, 0);
    tr(Wbt, WBTT, D, D, D, 0);

    k_m1<<<D, D, 0, stream>>>(WBGT, Wtt, M1T);
    k_c1<<<1, D, 0, stream>>>(WBGT, btt, C1);
    k_pack4<<<256, 256, 0, stream>>>(Wb, WB4);

    k_xg<<<SEQ, 1024, 0, stream>>>(text, wordvector, WihL, bihL, bhhL, XGF);
    k_xg<<<SEQ, 1024, 0, stream>>>(text, wordvector, WihR, bihR, bhhR, XGB);
    k_lstm<<<2, 1024, 0, stream>>>(XGF, XGB, WHLT, WHRT, WORDIN);
    k_prep2<<<SEQ + NREL + NENT, 256, 0, stream>>>(WORDIN, WTWT, WBWT, WTRT, WBET,
                                                   relvec, entvec, bt, bb,
                                                   TW, BW, RVb, EVb);
    k_main3<<<1, 1024, 0, stream>>>(TW, BW, RVb, EVb, WTMT, WTBT, WBTT, M1T, C1,
                                    WB4, Wp, bp, Wpl, bpl, btb, bbt,
                                    (float*)d_out);
}

// Round 6
// 54569.073 us; speedup vs baseline: 1.4018x; 1.0601x over previous
//
#include <hip/hip_runtime.h>
#include <float.h>

constexpr int SEQ  = 128;   // sentence length T
constexpr int D    = 256;   // DIM / STATEDIM
constexpr int G    = 1024;  // 4*DIM gate width
constexpr int NREL = 26;    // REL_COUNT + 1
constexpr int NENT = 7;

typedef float v2f __attribute__((ext_vector_type(2)));

// ---------------------------------------------------------------------------
// Generic strided transpose: out[k*rows + i] = in[i*in_stride + in_off + k]
// ---------------------------------------------------------------------------
__global__ void k_trans(const float* __restrict__ in, float* __restrict__ out,
                        int rows, int cols, int in_stride, int in_off)
{
    int idx = blockIdx.x * 256 + threadIdx.x;
    if (idx >= rows * cols) return;
    int i = idx % rows;
    int k = idx / rows;
    out[idx] = in[(size_t)i * in_stride + in_off + k];
}

// ---------------------------------------------------------------------------
// xg[t][j] = bih[j] + bhh[j] + sum_k wordvector[text[t]][k] * Wih[j][k]
// ---------------------------------------------------------------------------
__global__ __launch_bounds__(1024) void k_xg(
    const int* __restrict__ text, const float* __restrict__ wv,
    const float* __restrict__ Wih, const float* __restrict__ bih,
    const float* __restrict__ bhh, float* __restrict__ xg)
{
    int t = blockIdx.x, j = threadIdx.x;
    const float* x  = wv + (size_t)text[t] * D;
    const float* wr = Wih + (size_t)j * D;
    float acc = bih[j] + bhh[j];
    for (int k = 0; k < D; ++k) acc += x[k] * wr[k];
    xg[t * G + j] = acc;
}

// ---------------------------------------------------------------------------
// Sequential LSTM, one block per direction (grid=2), 1024 threads.
// ---------------------------------------------------------------------------
__global__ __launch_bounds__(1024) void k_lstm(
    const float* __restrict__ xgF, const float* __restrict__ xgB,
    const float* __restrict__ WHTF, const float* __restrict__ WHTB,
    float* __restrict__ wordin)
{
    int dir = blockIdx.x;
    const float* xg  = dir ? xgB  : xgF;
    const float* WHT = dir ? WHTB : WHTF;
    __shared__ float h[D], c[D], g[G];
    int j = threadIdx.x;
    if (j < D) { h[j] = 0.f; c[j] = 0.f; }
    __syncthreads();
    for (int s = 0; s < SEQ; ++s) {
        int t = dir ? (SEQ - 1 - s) : s;
        float acc = xg[t * G + j];
        for (int k = 0; k < D; ++k) acc += WHT[k * G + j] * h[k];
        g[j] = acc;
        __syncthreads();
        if (j < D) {
            float si = 1.f / (1.f + expf(-g[j]));
            float sf = 1.f / (1.f + expf(-g[D + j]));
            float gg = tanhf(g[2 * D + j]);
            float so = 1.f / (1.f + expf(-g[3 * D + j]));
            float cn = sf * c[j] + si * gg;
            float hn = so * tanhf(cn);
            c[j] = cn; h[j] = hn;
            wordin[t * (2 * D) + dir * D + j] = hn;
        }
        __syncthreads();
    }
}

// ---------------------------------------------------------------------------
// Parallel precompute after LSTM (TW/BW per word, RV per relation, EV per ent)
// ---------------------------------------------------------------------------
__global__ __launch_bounds__(256) void k_prep2(
    const float* __restrict__ wordin,
    const float* __restrict__ WTWT, const float* __restrict__ WBWT,
    const float* __restrict__ WTRT, const float* __restrict__ WBET,
    const float* __restrict__ relvec, const float* __restrict__ entvec,
    const float* __restrict__ btv, const float* __restrict__ bbv,
    float* __restrict__ TW, float* __restrict__ BW,
    float* __restrict__ RV, float* __restrict__ EV)
{
    int b = blockIdx.x, i = threadIdx.x;
    if (b < SEQ) {
        const float* w = wordin + b * (2 * D);
        float a1 = btv[i], a2 = bbv[i];
        for (int j = 0; j < 2 * D; ++j) {
            float wv = w[j];
            a1 += wv * WTWT[j * D + i];
            a2 += wv * WBWT[j * D + i];
        }
        TW[b * D + i] = a1;
        BW[b * D + i] = a2;
    } else if (b < SEQ + NREL) {
        int r = b - SEQ;
        const float* x = relvec + r * D;
        float a = 0.f;
        for (int k = 0; k < D; ++k) a += x[k] * WTRT[k * D + i];
        RV[r * D + i] = a;
    } else {
        int e = b - SEQ - NREL;
        const float* x = entvec + e * D;
        float a = 0.f;
        for (int k = 0; k < D; ++k) a += x[k] * WBET[k * D + i];
        EV[e * D + i] = a;
    }
}

// ---------------------------------------------------------------------------
// M1T[j*D + i] = sum_k WBGT[k*D+i] * Wtt[k*D+j]   (M1 = Wb_target @ Wtt)
// ---------------------------------------------------------------------------
__global__ __launch_bounds__(256) void k_m1(
    const float* __restrict__ WBGT, const float* __restrict__ Wtt,
    float* __restrict__ M1T)
{
    int j = blockIdx.x, i = threadIdx.x;
    float a = 0.f;
    for (int k = 0; k < D; ++k) a = fmaf(WBGT[k * D + i], Wtt[k * D + j], a);
    M1T[j * D + i] = a;
}

// c1[i] = sum_k WBGT[k*D+i] * btt[k]
__global__ __launch_bounds__(256) void k_c1(
    const float* __restrict__ WBGT, const float* __restrict__ btt,
    float* __restrict__ c1)
{
    int i = threadIdx.x;
    float a = 0.f;
    for (int k = 0; k < D; ++k) a = fmaf(WBGT[k * D + i], btt[k], a);
    c1[i] = a;
}

// ---------------------------------------------------------------------------
// Per-thread-contiguous pack of Wb_m for the 4-way split-k register matvec:
// WB4[tid*64 + kk] = Wb[i][768 + q*64 + kk],  tid = q*256+i  (1024 threads)
// ---------------------------------------------------------------------------
__global__ __launch_bounds__(256) void k_pack4(
    const float* __restrict__ Wb, float* __restrict__ WB4)
{
    int e = blockIdx.x * 256 + threadIdx.x;      // 0..65535
    int tid = e >> 6, kk = e & 63;
    int q = tid >> 8, i = tid & 255;
    WB4[e] = Wb[(size_t)i * (5 * D) + 3 * D + q * 64 + kk];
}

// ---------------------------------------------------------------------------
// Streamed split-k quarter matvec: Wcol points at W^T[k0*D + i] (k-major),
// x points at the LDS vector slice for this k-quarter. 4 independent chains.
// ---------------------------------------------------------------------------
__device__ inline float mv_q(const float* __restrict__ Wcol,
                             const float* __restrict__ x)
{
    float a0 = 0.f, a1 = 0.f, a2 = 0.f, a3 = 0.f;
    #pragma unroll
    for (int kk = 0; kk < 64; kk += 4) {
        a0 = fmaf(Wcol[(kk + 0) * D], x[kk + 0], a0);
        a1 = fmaf(Wcol[(kk + 1) * D], x[kk + 1], a1);
        a2 = fmaf(Wcol[(kk + 2) * D], x[kk + 2], a2);
        a3 = fmaf(Wcol[(kk + 3) * D], x[kk + 3], a3);
    }
    return (a0 + a1) + (a2 + a3);
}

// ---------------------------------------------------------------------------
// Softmax + first-occurrence argmax over n values living in lanes 0..n-1 of
// each W-lane group. Mimics reference: p = exp(l-max)/sum, argmax over p.
// Lanes >= n pass lv = -FLT_MAX; their p=-1 matches only bits >= n, so the
// ffsll result (lowest set bit) always comes from the real group. Wave-uniform.
// ---------------------------------------------------------------------------
template<int W>
__device__ inline void grp_smax(float lv, int n, int lane, int& am, float& pm)
{
    float mx = lv;
    #pragma unroll
    for (int off = W / 2; off; off >>= 1) mx = fmaxf(mx, __shfl_xor(mx, off));
    float e  = (lane < n) ? expf(lv - mx) : 0.f;
    float se = e;
    #pragma unroll
    for (int off = W / 2; off; off >>= 1) se += __shfl_xor(se, off);
    float p  = (lane < n) ? (e / se) : -1.f;
    float q  = p;
    #pragma unroll
    for (int off = W / 2; off; off >>= 1) q = fmaxf(q, __shfl_xor(q, off));
    unsigned long long mask = __ballot(p == q);
    am = __ffsll((long long)mask) - 1;
    pm = q;
}

// ---------------------------------------------------------------------------
// Sequential main kernel: 1 block, 1024 threads = 16 waves = 4 waves/SIMD.
// NO __launch_bounds__ macro: raw attributes only. amdgpu_waves_per_eu(4,4)
// pins the allocator's occupancy TARGET at the physical occupancy of this
// single block (4 waves/SIMD -> 512/4 = 128-VGPR budget). R1-R5 failure mode:
// default target (8/EU at 1024 thr) budgeted 64 VGPRs and spilled the
// 64-float weight array to scratch -> 3.5 GB HBM re-reads per dispatch.
// Demand here: 64 weight + ~45 working ~= 110 < 128.
// ---------------------------------------------------------------------------
__global__
__attribute__((amdgpu_flat_work_group_size(1024, 1024), amdgpu_waves_per_eu(4, 4)))
void k_main4(
    const float* __restrict__ TW,   const float* __restrict__ BW,
    const float* __restrict__ RV,   const float* __restrict__ EV,
    const float* __restrict__ WTMT, const float* __restrict__ WTBT,
    const float* __restrict__ WBTT, const float* __restrict__ M1T,
    const float* __restrict__ c1v,  const float* __restrict__ WB4,
    const float* __restrict__ Wp,   const float* __restrict__ bp,
    const float* __restrict__ Wpl,  const float* __restrict__ bpl,
    const float* __restrict__ btb,  const float* __restrict__ bbt,
    float* __restrict__ out)
{
    const int tid  = threadIdx.x;
    const int lane = tid & 63;
    const int lwv  = (tid >> 6) & 3;  // wave index within quarter
    const int q    = tid >> 8;        // k-quarter 0..3
    const int i    = tid & 255;       // output index
    const bool lower = (tid < 256);

    __shared__ __align__(16) float xbuf[2][D];
    __shared__ __align__(16) float psA[4][D], psB[4][D];
    __shared__ __align__(16) float mem[D], outv[D];
    __shared__ __align__(16) float Esh[NENT * D], WrSh[NENT * D];
    __shared__ float lpart[4][32];
    __shared__ float brSh[8];

    // register-resident W_bm quarter-column (per-thread contiguous pack)
    v2f w2[32];
    {
        const float4* src = reinterpret_cast<const float4*>(WB4) + tid * 16;
        #pragma unroll
        for (int k4 = 0; k4 < 16; ++k4) {
            float4 v = src[k4];
            w2[2 * k4 + 0] = (v2f){v.x, v.y};
            w2[2 * k4 + 1] = (v2f){v.z, v.w};
        }
    }
    // pin: forbid rematerialization of the weight loads
    #pragma unroll
    for (int k2 = 0; k2 < 32; ++k2) {
        double dp = __builtin_bit_cast(double, w2[k2]);
        asm volatile("" : "+v"(dp));
        w2[k2] = __builtin_bit_cast(v2f, dp);
    }
    for (int k = tid; k < NENT * D; k += 1024) Esh[k] = EV[k];
    if (lower) mem[i] = 0.f;
    __syncthreads();

    const float* WTMq = WTMT + (size_t)q * 64 * D + i;
    const float* WTBq = WTBT + (size_t)q * 64 * D + i;
    const float* WBTq = WBTT + (size_t)q * 64 * D + i;
    const float* M1q  = M1T  + (size_t)q * 64 * D + i;

    int rel = 0;

    for (int t = 0; t < SEQ; ++t) {
        // ---- top step: outp = tanh(TW[t] + RV[rel] + Wt_m @ mem) ----
        psA[q][i] = mv_q(WTMq, mem + q * 64);
        __syncthreads();
        if (lower) {
            float tot = psA[0][i] + psA[1][i] + psA[2][i] + psA[3][i] +
                        TW[t * D + i] + RV[rel * D + i];
            float outp = tanhf(tot);
            outv[i] = outp;
            #pragma unroll 2
            for (int r = 0; r < NREL; ++r) {
                float pp = outp * Wp[r * D + i];
                #pragma unroll
                for (int off = 32; off; off >>= 1) pp += __shfl_xor(pp, off);
                if (lane == 0) lpart[lwv][r] = pp;
            }
        }
        __syncthreads();
        float lv = -FLT_MAX;
        if (lane < NREL)
            lv = lpart[0][lane] + lpart[1][lane] + lpart[2][lane] +
                 lpart[3][lane] + bp[lane];
        int am; float pm;
        grp_smax<32>(lv, NREL, lane, am, pm);
        if (tid == 0) { out[t] = (float)am; out[SEQ + t] = pm; }
        const int action = am;   // wave-uniform

        if (action > 0) {
            rel = action;
            // memb0 = Wtb@outp + btb ;  btm = M1@outp + c1  (tgt folded away)
            psA[q][i] = mv_q(WTBq, outv + q * 64);
            psB[q][i] = mv_q(M1q,  outv + q * 64);
            const size_t wbase = (size_t)(action - 1) * NENT * D;
            for (int k = tid; k < NENT * D; k += 1024) WrSh[k] = Wpl[wbase + k];
            if (tid < NENT) brSh[tid] = bpl[(action - 1) * NENT + tid];
            __syncthreads();
            float btm = 0.f, bwc = 0.f;
            if (lower) {
                xbuf[0][i] = psA[0][i] + psA[1][i] + psA[2][i] + psA[3][i] +
                             btb[i];
                btm = psB[0][i] + psB[1][i] + psB[2][i] + psB[3][i] + c1v[i];
                bwc = BW[i];          // prefetch BW row 0
            }
            __syncthreads();

            int p = 0, ab = 0;
            for (int s = 0; s < SEQ; ++s) {
                // -- matvec quarter: packed f32 FMA from registers --
                const float4* xb =
                    reinterpret_cast<const float4*>(xbuf[p] + q * 64);
                v2f A0 = {0.f, 0.f}, A1 = {0.f, 0.f},
                    A2 = {0.f, 0.f}, A3 = {0.f, 0.f};
                #pragma unroll
                for (int k4 = 0; k4 < 16; k4 += 4) {
                    float4 x0 = xb[k4], x1 = xb[k4 + 1],
                           x2 = xb[k4 + 2], x3 = xb[k4 + 3];
                    A0 = __builtin_elementwise_fma(w2[2 * k4 + 0], (v2f){x0.x, x0.y}, A0);
                    A0 = __builtin_elementwise_fma(w2[2 * k4 + 1], (v2f){x0.z, x0.w}, A0);
                    A1 = __builtin_elementwise_fma(w2[2 * k4 + 2], (v2f){x1.x, x1.y}, A1);
                    A1 = __builtin_elementwise_fma(w2[2 * k4 + 3], (v2f){x1.z, x1.w}, A1);
                    A2 = __builtin_elementwise_fma(w2[2 * k4 + 4], (v2f){x2.x, x2.y}, A2);
                    A2 = __builtin_elementwise_fma(w2[2 * k4 + 5], (v2f){x2.z, x2.w}, A2);
                    A3 = __builtin_elementwise_fma(w2[2 * k4 + 6], (v2f){x3.x, x3.y}, A3);
                    A3 = __builtin_elementwise_fma(w2[2 * k4 + 7], (v2f){x3.z, x3.w}, A3);
                }
                v2f AS = (A0 + A1) + (A2 + A3);
                float ms = AS.x + AS.y;
                psA[q][i] = ms;
                __syncthreads();                       // barrier 1
                if (lower) {
                    float tot = ms + psA[1][i] + psA[2][i] + psA[3][i] +
                                bwc + Esh[ab * D + i] + btm;
                    float ob = tanhf(tot);
                    xbuf[p ^ 1][i] = ob;
                    #pragma unroll
                    for (int r = 0; r < NENT; ++r) {
                        float pp = ob * WrSh[r * D + i];
                        #pragma unroll
                        for (int off = 32; off; off >>= 1)
                            pp += __shfl_xor(pp, off);
                        if (lane == 0) lpart[lwv][r] = pp;
                    }
                    int sn = (s + 1 < SEQ) ? s + 1 : s;
                    bwc = BW[sn * D + i];              // prefetch next row
                }
                __syncthreads();                       // barrier 2
                float lv2 = -FLT_MAX;
                if (lane < NENT)
                    lv2 = lpart[0][lane] + lpart[1][lane] + lpart[2][lane] +
                          lpart[3][lane] + brSh[lane];
                int am2; float pm2;
                grp_smax<8>(lv2, NENT, lane, am2, pm2);
                if (tid == 0) {
                    out[2 * SEQ + t * SEQ + s] = (float)am2;
                    out[2 * SEQ + SEQ * SEQ + t * SEQ + s] = pm2;
                }
                ab = am2;        // wave-uniform register, no LDS roundtrip
                p ^= 1;
            }
            // mem = Wbt @ membf + bbt
            psA[q][i] = mv_q(WBTq, xbuf[p] + q * 64);
            __syncthreads();
            if (lower)
                mem[i] = psA[0][i] + psA[1][i] + psA[2][i] + psA[3][i] +
                         bbt[i];
            __syncthreads();
        } else {
            if (lower) mem[i] = outv[i];
            if (tid < SEQ) {
                out[2 * SEQ + t * SEQ + tid] = 0.f;
                out[2 * SEQ + SEQ * SEQ + t * SEQ + tid] = 0.f;
            }
            __syncthreads();
        }
    }
}

// ---------------------------------------------------------------------------
extern "C" void kernel_launch(void* const* d_in, const int* in_sizes, int n_in,
                              void* d_out, int out_size, void* d_ws, size_t ws_size,
                              hipStream_t stream)
{
    (void)in_sizes; (void)n_in; (void)out_size; (void)ws_size;
    const int*   text       = (const int*)  d_in[0];
    const float* wordvector = (const float*)d_in[1];
    const float* relvec     = (const float*)d_in[2];
    const float* entvec     = (const float*)d_in[3];
    const float* WihL = (const float*)d_in[4];  const float* WhhL = (const float*)d_in[5];
    const float* bihL = (const float*)d_in[6];  const float* bhhL = (const float*)d_in[7];
    const float* WihR = (const float*)d_in[8];  const float* WhhR = (const float*)d_in[9];
    const float* bihR = (const float*)d_in[10]; const float* bhhR = (const float*)d_in[11];
    const float* Wt   = (const float*)d_in[12]; const float* bt   = (const float*)d_in[13];
    const float* Wp   = (const float*)d_in[14]; const float* bp   = (const float*)d_in[15];
    const float* Wb   = (const float*)d_in[16]; const float* bb   = (const float*)d_in[17];
    const float* Wpl  = (const float*)d_in[18]; const float* bpl  = (const float*)d_in[19];
    const float* Wtt  = (const float*)d_in[20]; const float* btt  = (const float*)d_in[21];
    const float* Wtb  = (const float*)d_in[22]; const float* btb  = (const float*)d_in[23];
    const float* Wbt  = (const float*)d_in[24]; const float* bbt  = (const float*)d_in[25];

    float* ws = (float*)d_ws;
    size_t o = 0;
    auto take = [&](size_t n) { float* p = ws + o; o += n; return p; };
    float* XGF    = take(SEQ * G);
    float* XGB    = take(SEQ * G);
    float* WHLT   = take(D * G);
    float* WHRT   = take(D * G);
    float* WORDIN = take(SEQ * 2 * D);
    float* TW     = take(SEQ * D);
    float* BW     = take(SEQ * D);
    float* RVb    = take(NREL * D);
    float* EVb    = take(NENT * D);
    float* WTWT   = take(2 * D * D);
    float* WTRT   = take(D * D);
    float* WTMT   = take(D * D);
    float* WBWT   = take(2 * D * D);
    float* WBET   = take(D * D);
    float* WBGT   = take(D * D);
    float* WTBT   = take(D * D);
    float* WBTT   = take(D * D);
    float* M1T    = take(D * D);
    float* C1     = take(D);
    float* WB4    = take(1024 * 64);     // 1024 threads * 64 floats

    auto tr = [&](const float* in, float* outp, int rows, int cols, int stride, int off) {
        int n = rows * cols;
        k_trans<<<(n + 255) / 256, 256, 0, stream>>>(in, outp, rows, cols, stride, off);
    };
    tr(WhhL, WHLT, G, D, D, 0);          // WHLT[k*G + j] = WhhL[j][k]
    tr(WhhR, WHRT, G, D, D, 0);
    tr(Wt,  WTWT, D, 2 * D, G, 0);       // word part of Wt
    tr(Wt,  WTRT, D, D, G, 512);         // relvec part
    tr(Wt,  WTMT, D, D, G, 768);         // mem part
    tr(Wb,  WBWT, D, 2 * D, 5 * D, 0);   // word part of Wb
    tr(Wb,  WBET, D, D, 5 * D, 512);     // entvec part
    tr(Wb,  WBGT, D, D, 5 * D, 1024);    // target part (feeds M1/c1)
    tr(Wtb, WTBT, D, D, D, 0);
    tr(Wbt, WBTT, D, D, D, 0);

    k_m1<<<D, D, 0, stream>>>(WBGT, Wtt, M1T);
    k_c1<<<1, D, 0, stream>>>(WBGT, btt, C1);
    k_pack4<<<256, 256, 0, stream>>>(Wb, WB4);

    k_xg<<<SEQ, 1024, 0, stream>>>(text, wordvector, WihL, bihL, bhhL, XGF);
    k_xg<<<SEQ, 1024, 0, stream>>>(text, wordvector, WihR, bihR, bhhR, XGB);
    k_lstm<<<2, 1024, 0, stream>>>(XGF, XGB, WHLT, WHRT, WORDIN);
    k_prep2<<<SEQ + NREL + NENT, 256, 0, stream>>>(WORDIN, WTWT, WBWT, WTRT, WBET,
                                                   relvec, entvec, bt, bb,
                                                   TW, BW, RVb, EVb);
    k_main4<<<1, 1024, 0, stream>>>(TW, BW, RVb, EVb, WTMT, WTBT, WBTT, M1T, C1,
                                    WB4, Wp, bp, Wpl, bpl, btb, bbt,
                                    (float*)d_out);
}